// Round 8
// baseline (254.557 us; speedup 1.0000x reference)
//
#include <hip/hip_runtime.h>
#include <hip/hip_fp16.h>
#include <math.h>

#define N_NODES 50000
#define N_EDGES 1600000
#define N_GRAPHS 512
#define F_IN 9
#define H 64
#define N_BUCKETS ((N_NODES + 255) >> 8)     // 196
#define EPB 4096
#define N_SBLK ((N_EDGES + EPB - 1) / EPB)   // 391
#define FINE_CAP 10240                        // mean 8192, sd ~90 -> +22 sd

typedef _Float16 f16x8 __attribute__((ext_vector_type(8)));
typedef float f32x4 __attribute__((ext_vector_type(4)));
typedef float f32x2 __attribute__((ext_vector_type(2)));

__device__ __forceinline__ void pack_weights_body(
        const float* __restrict__ w1a, const float* __restrict__ w1b,
        const float* __restrict__ w2a, const float* __restrict__ w2b,
        const float* __restrict__ wr1,
        __half* __restrict__ pk1Ah, __half* __restrict__ pk1Al,
        __half* __restrict__ pk1Bh, __half* __restrict__ pk1Bl,
        __half* __restrict__ pkAh, __half* __restrict__ pkAl,
        __half* __restrict__ pkBh, __half* __restrict__ pkBl,
        __half* __restrict__ pkRh, __half* __restrict__ pkRl) {
    int t = threadIdx.x;
    for (int i = t; i < 2048; i += 512) {      // w1a: [64][9], K=32 zero-pad
        int j = i & 7, l = (i >> 3) & 63, tt = i >> 9;
        int q = l >> 4, n = l & 15;
        int k = q * 8 + j;
        float v = (k < F_IN) ? w1a[(tt * 16 + n) * F_IN + k] : 0.f;
        __half h = __float2half(v);
        pk1Ah[i] = h; pk1Al[i] = __float2half(v - __half2float(h));
    }
    for (int i = t; i < 4096; i += 512) {
        int j = i & 7, l = (i >> 3) & 63, c = (i >> 9) & 1, tt = i >> 10;
        int q = l >> 4, n = l & 15;
        int src = (tt * 16 + n) * H + c * 32 + q * 8 + j;
        float v1 = w1b[src], wa = w2a[src], wb = w2b[src];
        __half h1 = __float2half(v1), ah = __float2half(wa), bh = __float2half(wb);
        pk1Bh[i] = h1; pk1Bl[i] = __float2half(v1 - __half2float(h1));
        pkAh[i] = ah; pkAl[i] = __float2half(wa - __half2float(ah));
        pkBh[i] = bh; pkBl[i] = __float2half(wb - __half2float(bh));
    }
    for (int i = t; i < 2048; i += 512) {
        int j = i & 7, l = (i >> 3) & 63, c = (i >> 9) & 1, tt = i >> 10;
        int q = l >> 4, n = l & 15;
        float wr = wr1[(tt * 16 + n) * H + c * 32 + q * 8 + j];
        __half rh = __float2half(wr);
        pkRh[i] = rh; pkRl[i] = __float2half(wr - __half2float(rh));
    }
}

// ---------- bucket scatter (fixed-capacity buckets); block 0 packs weights ----------
__global__ void __launch_bounds__(512)
bucket_scatter(const int* __restrict__ ei,
               const float* __restrict__ ea,
               int* __restrict__ bnext,
               uint2* __restrict__ ebuk,
               const float* __restrict__ w1a,
               const float* __restrict__ w1b,
               const float* __restrict__ w2a,
               const float* __restrict__ w2b,
               const float* __restrict__ wr1,
               __half* pk1Ah, __half* pk1Al,
               __half* pk1Bh, __half* pk1Bl,
               __half* pkAh, __half* pkAl,
               __half* pkBh, __half* pkBl,
               __half* pkRh, __half* pkRl) {
    if (blockIdx.x == 0) {
        pack_weights_body(w1a, w1b, w2a, w2b, wr1, pk1Ah, pk1Al, pk1Bh, pk1Bl,
                          pkAh, pkAl, pkBh, pkBl, pkRh, pkRl);
        return;
    }
    __shared__ int cnt[N_BUCKETS];
    __shared__ int gbase[N_BUCKETS];
    for (int i = threadIdx.x; i < N_BUCKETS; i += 512) cnt[i] = 0;
    __syncthreads();
    int base = (blockIdx.x - 1) * EPB;
    int rk[8];
    unsigned pay[8];
#pragma unroll
    for (int j = 0; j < 8; ++j) {
        int e = base + j * 512 + threadIdx.x;
        rk[j] = -1;
        if (e < N_EDGES) {
            int d = ei[N_EDGES + e];
            int s = ei[e];
            float a = ea[e];
            pay[j] = ((unsigned)s << 16) |
                     (unsigned)__half_as_ushort(__float2half(a));
            int b = d >> 8;
            int r = atomicAdd(&cnt[b], 1);
            rk[j] = (b << 21) | ((d & 255) << 13) | r;
        }
    }
    __syncthreads();
    for (int i = threadIdx.x; i < N_BUCKETS; i += 512)
        gbase[i] = cnt[i] ? atomicAdd(&bnext[i], cnt[i]) : 0;
    __syncthreads();
#pragma unroll
    for (int j = 0; j < 8; ++j) {
        if (rk[j] < 0) continue;
        int b = rk[j] >> 21, dl = (rk[j] >> 13) & 255, r = rk[j] & 8191;
        int slot = gbase[b] + r;
        if (slot >= FINE_CAP) continue;
        ebuk[(size_t)b * FINE_CAP + slot] = make_uint2(pay[j], (unsigned)dl);
    }
}

#define UNPACK_ATTR(P) __half2float(__ushort_as_half((unsigned short)((P) & 0xffffu)))

// ---------- per-bucket fine sort -> node CSR + ep4, FUSED conv1 aggregation ----------
// After sorting the bucket's edges into LDS, each of the 8 waves aggregates
// conv1 for 32 of the block's 256 nodes directly from LDS (no ep4 re-read).
// x (1.8MB) gathers hit L2. Writes xs[n][32] via nt store.
__global__ void __launch_bounds__(512)
bucket_fine(const uint2* __restrict__ ebuk,
            const int* __restrict__ bnext,
            unsigned* __restrict__ ep4,
            int* __restrict__ starts, int* __restrict__ deg,
            const float* __restrict__ x,
            const float* __restrict__ e1w,
            const float* __restrict__ e1b,
            float* __restrict__ xs) {
    __shared__ unsigned sorted[FINE_CAP];
    __shared__ int cntN[256], offN[256], nxtN[256];
    __shared__ int wsum[4];
    int b = blockIdx.x;
    int base = b * FINE_CAP;
    int count = bnext[b];
    if (count > FINE_CAP) count = FINE_CAP;
    int tid = threadIdx.x;
    if (tid < 256) cntN[tid] = 0;
    __syncthreads();
    uint2 ev[20];                               // FINE_CAP/512 == 20
#pragma unroll
    for (int k = 0; k < 20; ++k) {
        int i = tid + k * 512;
        ev[k] = (i < count) ? ebuk[base + i] : make_uint2(0u, 0xFFFFFFFFu);
    }
#pragma unroll
    for (int k = 0; k < 20; ++k)
        if (ev[k].y < 256u) atomicAdd(&cntN[ev[k].y], 1);
    __syncthreads();
    int lane = tid & 63, wid = tid >> 6;
    int v = 0, incl = 0;
    if (tid < 256) {                     // waves 0-3 only (wave-uniform guard)
        v = cntN[tid]; incl = v;
#pragma unroll
        for (int off = 1; off < 64; off <<= 1) {
            int t = __shfl_up(incl, off, 64);
            if (lane >= off) incl += t;
        }
        if (lane == 63) wsum[wid] = incl;
    }
    __syncthreads();
    if (tid < 256) {
        int woff = 0;
        for (int w = 0; w < wid; ++w) woff += wsum[w];
        int excl = woff + incl - v;
        offN[tid] = excl;
        nxtN[tid] = 0;
        int n = (b << 8) + tid;
        if (n < N_NODES) { starts[n] = base + excl; deg[n] = v; }
    }
    __syncthreads();
#pragma unroll
    for (int k = 0; k < 20; ++k) {
        if (ev[k].y < 256u) {
            int r = atomicAdd(&nxtN[ev[k].y], 1);
            sorted[offN[ev[k].y] + r] = ev[k].x;
        }
    }
    __syncthreads();
    // write node-sorted edges for conv2's aggregation pass
    for (int i = tid; i < count; i += 512)
        ep4[base + i] = sorted[i];

    // ---- fused conv1 aggregation from LDS ----
    int slot = lane >> 4;                 // 0..3
    int f = lane & 15;
    bool act = f < F_IN;
    float wf = act ? e1w[f] : 0.f;
    float bf = act ? e1b[f] : 0.f;
    for (int i = 0; i < 32; ++i) {
        int nloc = wid * 32 + i;          // wave-uniform
        int n = (b << 8) + nloc;
        if (n >= N_NODES) break;
        int off = offN[nloc];
        int dgN = cntN[nloc];
        float acc = 0.f;
        int j = slot;
        for (; j + 12 < dgN; j += 16) {
            unsigned pa = sorted[off + j];
            unsigned pb = sorted[off + j + 4];
            unsigned pc = sorted[off + j + 8];
            unsigned pd = sorted[off + j + 12];
            float xa_ = act ? x[(pa >> 16) * F_IN + f] : 0.f;
            float xb_ = act ? x[(pb >> 16) * F_IN + f] : 0.f;
            float xc_ = act ? x[(pc >> 16) * F_IN + f] : 0.f;
            float xd_ = act ? x[(pd >> 16) * F_IN + f] : 0.f;
            if (act) {
                acc += fmaxf(xa_ + UNPACK_ATTR(pa) * wf + bf, 0.f)
                     + fmaxf(xb_ + UNPACK_ATTR(pb) * wf + bf, 0.f)
                     + fmaxf(xc_ + UNPACK_ATTR(pc) * wf + bf, 0.f)
                     + fmaxf(xd_ + UNPACK_ATTR(pd) * wf + bf, 0.f);
            }
        }
        for (; j < dgN; j += 4) {
            unsigned p = sorted[off + j];
            float xv = act ? x[(p >> 16) * F_IN + f] : 0.f;
            float m = xv + UNPACK_ATTR(p) * wf + bf;
            acc += act ? fmaxf(m, 0.f) : 0.f;
        }
        acc += __shfl_xor(acc, 16, 64);
        acc += __shfl_xor(acc, 32, 64);
        if (lane < 32) {
            float o = (lane < F_IN) ? x[n * F_IN + lane] + acc : 0.f;
            __builtin_nontemporal_store(o, xs + n * 32 + lane);
        }
    }
}

__device__ __forceinline__ void split8(const float* __restrict__ v,
                                       f16x8& hi, f16x8& lo) {
#pragma unroll
    for (int j = 0; j < 8; ++j) {
        _Float16 h = (_Float16)v[j];
        hi[j] = h;
        lo[j] = (_Float16)(v[j] - (float)h);
    }
}

#define TILE3(C, A0H, A0L, A1H, A1L, PH, PL, T) do {                          \
        f16x8 b0h = *(const f16x8*)((PH) + (((T) * 2 + 0) * 64 + lane) * 8);  \
        f16x8 b0l = *(const f16x8*)((PL) + (((T) * 2 + 0) * 64 + lane) * 8);  \
        f16x8 b1h = *(const f16x8*)((PH) + (((T) * 2 + 1) * 64 + lane) * 8);  \
        f16x8 b1l = *(const f16x8*)((PL) + (((T) * 2 + 1) * 64 + lane) * 8);  \
        C = __builtin_amdgcn_mfma_f32_16x16x32_f16(A0H, b0h, C, 0, 0, 0);     \
        C = __builtin_amdgcn_mfma_f32_16x16x32_f16(A0L, b0h, C, 0, 0, 0);     \
        C = __builtin_amdgcn_mfma_f32_16x16x32_f16(A0H, b0l, C, 0, 0, 0);     \
        C = __builtin_amdgcn_mfma_f32_16x16x32_f16(A1H, b1h, C, 0, 0, 0);     \
        C = __builtin_amdgcn_mfma_f32_16x16x32_f16(A1L, b1h, C, 0, 0, 0);     \
        C = __builtin_amdgcn_mfma_f32_16x16x32_f16(A1H, b1l, C, 0, 0, 0);     \
    } while (0)

// ---------- conv1 node MLP via split-fp16 MFMA; writes interleaved h1[n][64] ----------
__global__ void node1_kernel(const float* __restrict__ xs,
                             const __half* __restrict__ pk1Ah, const __half* __restrict__ pk1Al,
                             const float* __restrict__ b1a,
                             const __half* __restrict__ pk1Bh, const __half* __restrict__ pk1Bl,
                             const float* __restrict__ b1b,
                             __half* __restrict__ h1) {
    __shared__ float hbuf[4][16][68];
    int wv = threadIdx.x >> 6;
    int lane = threadIdx.x & 63;
    int gwave = blockIdx.x * 4 + wv;
    bool active = gwave < (N_NODES / 16);
    int base = active ? gwave * 16 : 0;
    int m = lane & 15, q = lane >> 4;
    const _Float16* pAh = (const _Float16*)pk1Ah;
    const _Float16* pAl = (const _Float16*)pk1Al;
    const _Float16* pBh = (const _Float16*)pk1Bh;
    const _Float16* pBl = (const _Float16*)pk1Bl;

    f16x8 ah, al;
    split8(xs + (size_t)(base + m) * 32 + q * 8, ah, al);
#pragma unroll
    for (int t = 0; t < 4; ++t) {
        f32x4 c = {0.f, 0.f, 0.f, 0.f};
        f16x8 bh = *(const f16x8*)(pAh + (t * 64 + lane) * 8);
        f16x8 bl = *(const f16x8*)(pAl + (t * 64 + lane) * 8);
        c = __builtin_amdgcn_mfma_f32_16x16x32_f16(ah, bh, c, 0, 0, 0);
        c = __builtin_amdgcn_mfma_f32_16x16x32_f16(al, bh, c, 0, 0, 0);
        c = __builtin_amdgcn_mfma_f32_16x16x32_f16(ah, bl, c, 0, 0, 0);
        float bias = b1a[t * 16 + m];
#pragma unroll
        for (int r = 0; r < 4; ++r)
            hbuf[wv][q * 4 + r][t * 16 + m] = fmaxf(c[r] + bias, 0.f);
    }
    __syncthreads();
    f16x8 a0h, a0l, a1h, a1l;
    split8(&hbuf[wv][m][q * 8], a0h, a0l);
    split8(&hbuf[wv][m][32 + q * 8], a1h, a1l);
    float tmp[4][4];
#pragma unroll
    for (int t = 0; t < 4; ++t) {
        f32x4 c = {0.f, 0.f, 0.f, 0.f};
        TILE3(c, a0h, a0l, a1h, a1l, pBh, pBl, t);
        float bias = b1b[t * 16 + m];
#pragma unroll
        for (int r = 0; r < 4; ++r)
            tmp[t][r] = fmaxf(c[r] + bias, 0.f);
    }
    __syncthreads();
#pragma unroll
    for (int t = 0; t < 4; ++t)
#pragma unroll
        for (int r = 0; r < 4; ++r)
            hbuf[wv][q * 4 + r][t * 16 + m] = tmp[t][r];
    __syncthreads();
    if (active) {
        int nn = lane >> 2, part = lane & 3;
        f16x8 vlo, vhi;
        const float* rlo = &hbuf[wv][nn][part * 8];
        const float* rhi = &hbuf[wv][nn][32 + part * 8];
#pragma unroll
        for (int j = 0; j < 8; ++j) {
            vlo[j] = (_Float16)rlo[j];
            vhi[j] = (_Float16)rhi[j];
        }
        *(f16x8*)(h1 + (size_t)(base + nn) * 64 + part * 8) = vlo;
        *(f16x8*)(h1 + (size_t)(base + nn) * 64 + 32 + part * 8) = vhi;
    }
}

// ---------- conv2 aggregation, packed-pair form ----------
__global__ void aggphase2_kernel(const __half* __restrict__ h1,
                                 const int* __restrict__ starts,
                                 const int* __restrict__ deg,
                                 const unsigned* __restrict__ ep4,
                                 const float* __restrict__ ew,
                                 const float* __restrict__ eb,
                                 float* __restrict__ htot) {
    int n = blockIdx.x * (blockDim.x >> 6) + (threadIdx.x >> 6);
    int lane = threadIdx.x & 63;
    if (n >= N_NODES) return;
    int half = lane >> 5;                // which edge of the pair
    int l = lane & 31;                   // feature-pair index
    int s0 = starts[n], dg = deg[n];
    const unsigned* ep = ep4 + s0;
    const unsigned* h1u = (const unsigned*)h1;   // row stride 32 uints
    float2 w2 = *(const float2*)(ew + 2 * l);
    float2 b2 = *(const float2*)(eb + 2 * l);
    float acc0 = 0.f, acc1 = 0.f;
#define EDGE2(P, V) do {                                                   \
        float a_ = UNPACK_ATTR(P);                                         \
        __half2 hv_ = *(const __half2*)&(V);                               \
        float2 vf_ = __half22float2(hv_);                                  \
        acc0 += fmaxf(vf_.x + a_ * w2.x + b2.x, 0.f);                      \
        acc1 += fmaxf(vf_.y + a_ * w2.y + b2.y, 0.f);                      \
    } while (0)
    int j = 0;
    for (; j + 8 <= dg; j += 8) {
        unsigned p0 = ep[j + 0 + half], p1 = ep[j + 2 + half];
        unsigned p2 = ep[j + 4 + half], p3 = ep[j + 6 + half];
        unsigned v0 = h1u[(size_t)(p0 >> 16) * 32 + l];
        unsigned v1 = h1u[(size_t)(p1 >> 16) * 32 + l];
        unsigned v2 = h1u[(size_t)(p2 >> 16) * 32 + l];
        unsigned v3 = h1u[(size_t)(p3 >> 16) * 32 + l];
        EDGE2(p0, v0); EDGE2(p1, v1); EDGE2(p2, v2); EDGE2(p3, v3);
    }
    for (; j + 2 <= dg; j += 2) {
        unsigned p = ep[j + half];
        unsigned v = h1u[(size_t)(p >> 16) * 32 + l];
        EDGE2(p, v);
    }
    if (j < dg && half == 0) {
        unsigned p = ep[j];
        unsigned v = h1u[(size_t)(p >> 16) * 32 + l];
        EDGE2(p, v);
    }
#undef EDGE2
    acc0 += __shfl_xor(acc0, 32, 64);
    acc1 += __shfl_xor(acc1, 32, 64);
    if (half == 0) {
        unsigned sv = h1u[(size_t)n * 32 + l];
        float2 sf = __half22float2(*(const __half2*)&sv);
        f32x2 o;
        o[0] = sf.x + acc0;
        o[1] = sf.y + acc1;
        __builtin_nontemporal_store(o, (f32x2*)(htot + (size_t)n * 64 + 2 * l));
    }
}

// ---------- node2 via split-fp16 MFMA; writes pi and accumulates te ----------
__global__ void node2_kernel(const float* __restrict__ htot,
                             const __half* __restrict__ pkAh, const __half* __restrict__ pkAl,
                             const float* __restrict__ b2a,
                             const __half* __restrict__ pkBh, const __half* __restrict__ pkBl,
                             const float* __restrict__ b2b,
                             const __half* __restrict__ pkRh, const __half* __restrict__ pkRl,
                             const float* __restrict__ br1,
                             const float* __restrict__ wr2,
                             const float* __restrict__ br2,
                             const int* __restrict__ term,
                             const int* __restrict__ batch,
                             const float* __restrict__ ccost,
                             float* __restrict__ pi,
                             float* __restrict__ te) {
    __shared__ float hbuf[4][16][68];
    int wv = threadIdx.x >> 6;
    int lane = threadIdx.x & 63;
    int gwave = blockIdx.x * 4 + wv;
    bool active = gwave < (N_NODES / 16);
    int base = active ? gwave * 16 : 0;
    int m = lane & 15, q = lane >> 4;
    const _Float16* pAh = (const _Float16*)pkAh;
    const _Float16* pAl = (const _Float16*)pkAl;
    const _Float16* pBh = (const _Float16*)pkBh;
    const _Float16* pBl = (const _Float16*)pkBl;
    const _Float16* pRh = (const _Float16*)pkRh;
    const _Float16* pRl = (const _Float16*)pkRl;

    f16x8 a0h, a0l, a1h, a1l;
    {
        const float* hrow = htot + (size_t)(base + m) * 64;
        split8(hrow + q * 8, a0h, a0l);
        split8(hrow + 32 + q * 8, a1h, a1l);
    }
#pragma unroll
    for (int t = 0; t < 4; ++t) {
        f32x4 c = {0.f, 0.f, 0.f, 0.f};
        TILE3(c, a0h, a0l, a1h, a1l, pAh, pAl, t);
        float bias = b2a[t * 16 + m];
#pragma unroll
        for (int r = 0; r < 4; ++r)
            hbuf[wv][q * 4 + r][t * 16 + m] = fmaxf(c[r] + bias, 0.f);
    }
    __syncthreads();
    split8(&hbuf[wv][m][q * 8], a0h, a0l);
    split8(&hbuf[wv][m][32 + q * 8], a1h, a1l);
    float tmp[4][4];
#pragma unroll
    for (int t = 0; t < 4; ++t) {
        f32x4 c = {0.f, 0.f, 0.f, 0.f};
        TILE3(c, a0h, a0l, a1h, a1l, pBh, pBl, t);
        float bias = b2b[t * 16 + m];
#pragma unroll
        for (int r = 0; r < 4; ++r)
            tmp[t][r] = fmaxf(c[r] + bias, 0.f);
    }
    __syncthreads();
#pragma unroll
    for (int t = 0; t < 4; ++t)
#pragma unroll
        for (int r = 0; r < 4; ++r)
            hbuf[wv][q * 4 + r][t * 16 + m] = tmp[t][r];
    __syncthreads();
    split8(&hbuf[wv][m][q * 8], a0h, a0l);
    split8(&hbuf[wv][m][32 + q * 8], a1h, a1l);
    float partial[4] = {0.f, 0.f, 0.f, 0.f};
#pragma unroll
    for (int t = 0; t < 2; ++t) {
        f32x4 c = {0.f, 0.f, 0.f, 0.f};
        TILE3(c, a0h, a0l, a1h, a1l, pRh, pRl, t);
        float bias = br1[t * 16 + m];
        float wv2 = wr2[t * 16 + m];
#pragma unroll
        for (int r = 0; r < 4; ++r)
            partial[r] += fmaxf(c[r] + bias, 0.f) * wv2;
    }
#pragma unroll
    for (int off = 1; off < 16; off <<= 1) {
        partial[0] += __shfl_xor(partial[0], off, 64);
        partial[1] += __shfl_xor(partial[1], off, 64);
        partial[2] += __shfl_xor(partial[2], off, 64);
        partial[3] += __shfl_xor(partial[3], off, 64);
    }
    if (active && m == 0) {
#pragma unroll
        for (int r = 0; r < 4; ++r) {
            int n = base + q * 4 + r;
            float z = partial[r] + br2[0];
            float sig = 1.f / (1.f + expf(-z));
            float pv = sig * (1.f - (float)term[n]);
            pi[n] = pv;
            float contrib = pv * ccost[n];
            if (contrib != 0.f) atomicAdd(&te[batch[n]], contrib);
        }
    }
}

__global__ void final_kernel(const float* __restrict__ pi,
                             const int* __restrict__ batch,
                             const float* __restrict__ Btot,
                             const float* __restrict__ te,
                             float* __restrict__ out) {
    int n = blockIdx.x * blockDim.x + threadIdx.x;
    if (n >= N_NODES) return;
    int b = batch[n];
    float ratio = fminf(Btot[b] / (te[b] + 1e-12f), 1.f);
    out[n] = pi[n] * ratio;
}

extern "C" void kernel_launch(void* const* d_in, const int* in_sizes, int n_in,
                              void* d_out, int out_size, void* d_ws, size_t ws_size,
                              hipStream_t stream) {
    const float* x     = (const float*)d_in[0];
    const int*   ei    = (const int*)d_in[1];
    const float* ea    = (const float*)d_in[2];
    const int*   batch = (const int*)d_in[3];
    const float* Btot  = (const float*)d_in[4];
    const int*   term  = (const int*)d_in[5];
    const float* ccost = (const float*)d_in[6];
    const float* e1w   = (const float*)d_in[7];
    const float* e1b   = (const float*)d_in[8];
    const float* w1a   = (const float*)d_in[9];
    const float* b1a   = (const float*)d_in[10];
    const float* w1b   = (const float*)d_in[11];
    const float* b1b   = (const float*)d_in[12];
    const float* e2w   = (const float*)d_in[13];
    const float* e2b   = (const float*)d_in[14];
    const float* w2a   = (const float*)d_in[15];
    const float* b2a   = (const float*)d_in[16];
    const float* w2b   = (const float*)d_in[17];
    const float* b2b   = (const float*)d_in[18];
    const float* wr1   = (const float*)d_in[19];
    const float* br1   = (const float*)d_in[20];
    const float* wr2   = (const float*)d_in[21];
    const float* br2   = (const float*)d_in[22];

    char* p = (char*)d_ws;
    int*      bnext  = (int*)p;      p += sizeof(int)      * 256;       // zeroed
    float*    te     = (float*)p;    p += sizeof(float)    * N_GRAPHS;  // zeroed
    int*      starts = (int*)p;      p += sizeof(int)      * N_NODES;
    int*      deg    = (int*)p;      p += sizeof(int)      * N_NODES;
    p = (char*)(((size_t)p + 15) & ~(size_t)15);
    uint2*    ebuk   = (uint2*)p;    p += sizeof(uint2)    * (size_t)N_BUCKETS * FINE_CAP;
    unsigned* ep4    = (unsigned*)p; p += sizeof(unsigned) * (size_t)N_BUCKETS * FINE_CAP;
    __half*   h1     = (__half*)p;   p += sizeof(__half)   * (size_t)N_NODES * 64;
    float*    htot   = (float*)p;    p += sizeof(float)    * (size_t)N_NODES * 64;
    float*    xs     = (float*)p;    p += sizeof(float)    * (size_t)N_NODES * 32;
    float*    pi     = (float*)p;    p += sizeof(float)    * N_NODES;
    __half*   pk1Ah  = (__half*)p;   p += sizeof(__half)   * 2048;
    __half*   pk1Al  = (__half*)p;   p += sizeof(__half)   * 2048;
    __half*   pk1Bh  = (__half*)p;   p += sizeof(__half)   * 4096;
    __half*   pk1Bl  = (__half*)p;   p += sizeof(__half)   * 4096;
    __half*   pkAh   = (__half*)p;   p += sizeof(__half)   * 4096;
    __half*   pkAl   = (__half*)p;   p += sizeof(__half)   * 4096;
    __half*   pkBh   = (__half*)p;   p += sizeof(__half)   * 4096;
    __half*   pkBl   = (__half*)p;   p += sizeof(__half)   * 4096;
    __half*   pkRh   = (__half*)p;   p += sizeof(__half)   * 2048;
    __half*   pkRl   = (__half*)p;   p += sizeof(__half)   * 2048;
    float*    out    = (float*)d_out;

    hipMemsetAsync(d_ws, 0, sizeof(int) * 256 + sizeof(float) * N_GRAPHS, stream);

    bucket_scatter<<<1 + N_SBLK, 512, 0, stream>>>(ei, ea, bnext, ebuk,
                                                   w1a, w1b, w2a, w2b, wr1,
                                                   pk1Ah, pk1Al, pk1Bh, pk1Bl,
                                                   pkAh, pkAl, pkBh, pkBl, pkRh, pkRl);
    bucket_fine<<<N_BUCKETS, 512, 0, stream>>>(ebuk, bnext, ep4, starts, deg,
                                               x, e1w, e1b, xs);
    node1_kernel<<<(N_NODES / 16 + 3) / 4, 256, 0, stream>>>(xs, pk1Ah, pk1Al, b1a,
                                                             pk1Bh, pk1Bl, b1b, h1);
    aggphase2_kernel<<<(N_NODES + 3) / 4, 256, 0, stream>>>(h1, starts, deg, ep4,
                                                            e2w, e2b, htot);
    node2_kernel<<<(N_NODES / 16 + 3) / 4, 256, 0, stream>>>(htot,
                                                             pkAh, pkAl, b2a,
                                                             pkBh, pkBl, b2b,
                                                             pkRh, pkRl, br1,
                                                             wr2, br2, term,
                                                             batch, ccost, pi, te);
    final_kernel<<<(N_NODES + 255) / 256, 256, 0, stream>>>(pi, batch, Btot, te, out);
}

// Round 9
// 236.275 us; speedup vs baseline: 1.0774x; 1.0774x over previous
//
#include <hip/hip_runtime.h>
#include <hip/hip_fp16.h>
#include <math.h>

#define N_NODES 50000
#define N_EDGES 1600000
#define N_GRAPHS 512
#define F_IN 9
#define H 64
#define EPB 4096
#define N_SBLK ((N_EDGES + EPB - 1) / EPB)   // 391
// 64-node fine buckets: 782 blocks (~3/CU) for sort parallelism
#define BUCKET_NODES 64
#define N_FBUK ((N_NODES + BUCKET_NODES - 1) / BUCKET_NODES)   // 782
#define FCAP 2816                            // mean 2048, sd ~45 -> +17 sd

typedef _Float16 f16x8 __attribute__((ext_vector_type(8)));
typedef float f32x4 __attribute__((ext_vector_type(4)));
typedef float f32x2 __attribute__((ext_vector_type(2)));

__device__ __forceinline__ void pack_weights_body(
        const float* __restrict__ w1a, const float* __restrict__ w1b,
        const float* __restrict__ w2a, const float* __restrict__ w2b,
        const float* __restrict__ wr1,
        __half* __restrict__ pk1Ah, __half* __restrict__ pk1Al,
        __half* __restrict__ pk1Bh, __half* __restrict__ pk1Bl,
        __half* __restrict__ pkAh, __half* __restrict__ pkAl,
        __half* __restrict__ pkBh, __half* __restrict__ pkBl,
        __half* __restrict__ pkRh, __half* __restrict__ pkRl) {
    int t = threadIdx.x;
    for (int i = t; i < 2048; i += 512) {      // w1a: [64][9], K=32 zero-pad
        int j = i & 7, l = (i >> 3) & 63, tt = i >> 9;
        int q = l >> 4, n = l & 15;
        int k = q * 8 + j;
        float v = (k < F_IN) ? w1a[(tt * 16 + n) * F_IN + k] : 0.f;
        __half h = __float2half(v);
        pk1Ah[i] = h; pk1Al[i] = __float2half(v - __half2float(h));
    }
    for (int i = t; i < 4096; i += 512) {
        int j = i & 7, l = (i >> 3) & 63, c = (i >> 9) & 1, tt = i >> 10;
        int q = l >> 4, n = l & 15;
        int src = (tt * 16 + n) * H + c * 32 + q * 8 + j;
        float v1 = w1b[src], wa = w2a[src], wb = w2b[src];
        __half h1 = __float2half(v1), ah = __float2half(wa), bh = __float2half(wb);
        pk1Bh[i] = h1; pk1Bl[i] = __float2half(v1 - __half2float(h1));
        pkAh[i] = ah; pkAl[i] = __float2half(wa - __half2float(ah));
        pkBh[i] = bh; pkBl[i] = __float2half(wb - __half2float(bh));
    }
    for (int i = t; i < 2048; i += 512) {
        int j = i & 7, l = (i >> 3) & 63, c = (i >> 9) & 1, tt = i >> 10;
        int q = l >> 4, n = l & 15;
        float wr = wr1[(tt * 16 + n) * H + c * 32 + q * 8 + j];
        __half rh = __float2half(wr);
        pkRh[i] = rh; pkRl[i] = __float2half(wr - __half2float(rh));
    }
}

// ---------- bucket scatter (fixed-capacity buckets); block 0 packs weights ----------
// rk packing: b(10b)<<19 | dl(6b)<<13 | r(13b)
__global__ void __launch_bounds__(512)
bucket_scatter(const int* __restrict__ ei,
               const float* __restrict__ ea,
               int* __restrict__ bnext,
               uint2* __restrict__ ebuk,
               const float* __restrict__ w1a,
               const float* __restrict__ w1b,
               const float* __restrict__ w2a,
               const float* __restrict__ w2b,
               const float* __restrict__ wr1,
               __half* pk1Ah, __half* pk1Al,
               __half* pk1Bh, __half* pk1Bl,
               __half* pkAh, __half* pkAl,
               __half* pkBh, __half* pkBl,
               __half* pkRh, __half* pkRl) {
    if (blockIdx.x == 0) {
        pack_weights_body(w1a, w1b, w2a, w2b, wr1, pk1Ah, pk1Al, pk1Bh, pk1Bl,
                          pkAh, pkAl, pkBh, pkBl, pkRh, pkRl);
        return;
    }
    __shared__ int cnt[N_FBUK];
    __shared__ int gbase[N_FBUK];
    for (int i = threadIdx.x; i < N_FBUK; i += 512) cnt[i] = 0;
    __syncthreads();
    int base = (blockIdx.x - 1) * EPB;
    int rk[8];
    unsigned pay[8];
#pragma unroll
    for (int j = 0; j < 8; ++j) {
        int e = base + j * 512 + threadIdx.x;
        rk[j] = -1;
        if (e < N_EDGES) {
            int d = ei[N_EDGES + e];
            int s = ei[e];
            float a = ea[e];
            pay[j] = ((unsigned)s << 16) |
                     (unsigned)__half_as_ushort(__float2half(a));
            int b = d >> 6;
            int r = atomicAdd(&cnt[b], 1);
            rk[j] = (b << 19) | ((d & 63) << 13) | r;
        }
    }
    __syncthreads();
    for (int i = threadIdx.x; i < N_FBUK; i += 512)
        gbase[i] = cnt[i] ? atomicAdd(&bnext[i], cnt[i]) : 0;
    __syncthreads();
#pragma unroll
    for (int j = 0; j < 8; ++j) {
        if (rk[j] < 0) continue;
        int b = rk[j] >> 19, dl = (rk[j] >> 13) & 63, r = rk[j] & 8191;
        int slot = gbase[b] + r;
        if (slot >= FCAP) continue;
        ebuk[(size_t)b * FCAP + slot] = make_uint2(pay[j], (unsigned)dl);
    }
}

// ---------- per-bucket fine sort -> node CSR + node-sorted ep4 ----------
// 64-node buckets, 782 blocks (~3/CU), ~12KB LDS: latency hidden by waves.
__global__ void __launch_bounds__(512)
bucket_fine(const uint2* __restrict__ ebuk,
            const int* __restrict__ bnext,
            unsigned* __restrict__ ep4,
            int* __restrict__ starts, int* __restrict__ deg) {
    __shared__ unsigned sorted[FCAP];
    __shared__ int cntN[BUCKET_NODES], offN[BUCKET_NODES], nxtN[BUCKET_NODES];
    int b = blockIdx.x;
    int base = b * FCAP;
    int count = bnext[b];
    if (count > FCAP) count = FCAP;
    int tid = threadIdx.x;
    if (tid < BUCKET_NODES) cntN[tid] = 0;
    __syncthreads();
    uint2 ev[6];                                // FCAP/512 = 5.5 -> 6
#pragma unroll
    for (int k = 0; k < 6; ++k) {
        int i = tid + k * 512;
        ev[k] = (i < count) ? ebuk[base + i] : make_uint2(0u, 0xFFFFFFFFu);
    }
#pragma unroll
    for (int k = 0; k < 6; ++k)
        if (ev[k].y < (unsigned)BUCKET_NODES) atomicAdd(&cntN[ev[k].y], 1);
    __syncthreads();
    if (tid < 64) {                     // wave 0: 64-entry scan in one wave
        int v = cntN[tid];
        int incl = v;
#pragma unroll
        for (int off = 1; off < 64; off <<= 1) {
            int t = __shfl_up(incl, off, 64);
            if (tid >= off) incl += t;
        }
        int excl = incl - v;
        offN[tid] = excl;
        nxtN[tid] = 0;
        int n = (b << 6) + tid;
        if (n < N_NODES) { starts[n] = base + excl; deg[n] = v; }
    }
    __syncthreads();
#pragma unroll
    for (int k = 0; k < 6; ++k) {
        if (ev[k].y < (unsigned)BUCKET_NODES) {
            int r = atomicAdd(&nxtN[ev[k].y], 1);
            sorted[offN[ev[k].y] + r] = ev[k].x;
        }
    }
    __syncthreads();
    for (int i = tid; i < count; i += 512)
        ep4[base + i] = sorted[i];
}

#define UNPACK_ATTR(P) __half2float(__ushort_as_half((unsigned short)((P) & 0xffffu)))

// ---------- conv1 aggregation: writes xs[n][32] = (x + agg, zero-padded) ----------
__global__ void agg1_kernel(const float* __restrict__ x,
                            const int* __restrict__ starts,
                            const int* __restrict__ deg,
                            const unsigned* __restrict__ ep4,
                            const float* __restrict__ e1w,
                            const float* __restrict__ e1b,
                            float* __restrict__ xs) {
    int n = blockIdx.x * (blockDim.x >> 6) + (threadIdx.x >> 6);
    int lane = threadIdx.x & 63;
    if (n >= N_NODES) return;
    int slot = lane >> 4;
    int f = lane & 15;
    int s0 = starts[n], dg = deg[n];
    bool act = f < F_IN;
    float wf = act ? e1w[f] : 0.f;
    float bf = act ? e1b[f] : 0.f;
    float acc = 0.f;
    int j = slot;
    for (; j + 12 < dg; j += 16) {
        unsigned pa = ep4[s0 + j];
        unsigned pb = ep4[s0 + j + 4];
        unsigned pc = ep4[s0 + j + 8];
        unsigned pd = ep4[s0 + j + 12];
        float xa_ = act ? x[(pa >> 16) * F_IN + f] : 0.f;
        float xb_ = act ? x[(pb >> 16) * F_IN + f] : 0.f;
        float xc_ = act ? x[(pc >> 16) * F_IN + f] : 0.f;
        float xd_ = act ? x[(pd >> 16) * F_IN + f] : 0.f;
        if (act) {
            acc += fmaxf(xa_ + UNPACK_ATTR(pa) * wf + bf, 0.f)
                 + fmaxf(xb_ + UNPACK_ATTR(pb) * wf + bf, 0.f)
                 + fmaxf(xc_ + UNPACK_ATTR(pc) * wf + bf, 0.f)
                 + fmaxf(xd_ + UNPACK_ATTR(pd) * wf + bf, 0.f);
        }
    }
    for (; j < dg; j += 4) {
        unsigned p = ep4[s0 + j];
        float xv = act ? x[(p >> 16) * F_IN + f] : 0.f;
        float m = xv + UNPACK_ATTR(p) * wf + bf;
        acc += act ? fmaxf(m, 0.f) : 0.f;
    }
    acc += __shfl_xor(acc, 16, 64);
    acc += __shfl_xor(acc, 32, 64);
    if (lane < 32) {
        float v = (lane < F_IN) ? x[n * F_IN + lane] + acc : 0.f;
        __builtin_nontemporal_store(v, xs + n * 32 + lane);
    }
}

__device__ __forceinline__ void split8(const float* __restrict__ v,
                                       f16x8& hi, f16x8& lo) {
#pragma unroll
    for (int j = 0; j < 8; ++j) {
        _Float16 h = (_Float16)v[j];
        hi[j] = h;
        lo[j] = (_Float16)(v[j] - (float)h);
    }
}

#define TILE3(C, A0H, A0L, A1H, A1L, PH, PL, T) do {                          \
        f16x8 b0h = *(const f16x8*)((PH) + (((T) * 2 + 0) * 64 + lane) * 8);  \
        f16x8 b0l = *(const f16x8*)((PL) + (((T) * 2 + 0) * 64 + lane) * 8);  \
        f16x8 b1h = *(const f16x8*)((PH) + (((T) * 2 + 1) * 64 + lane) * 8);  \
        f16x8 b1l = *(const f16x8*)((PL) + (((T) * 2 + 1) * 64 + lane) * 8);  \
        C = __builtin_amdgcn_mfma_f32_16x16x32_f16(A0H, b0h, C, 0, 0, 0);     \
        C = __builtin_amdgcn_mfma_f32_16x16x32_f16(A0L, b0h, C, 0, 0, 0);     \
        C = __builtin_amdgcn_mfma_f32_16x16x32_f16(A0H, b0l, C, 0, 0, 0);     \
        C = __builtin_amdgcn_mfma_f32_16x16x32_f16(A1H, b1h, C, 0, 0, 0);     \
        C = __builtin_amdgcn_mfma_f32_16x16x32_f16(A1L, b1h, C, 0, 0, 0);     \
        C = __builtin_amdgcn_mfma_f32_16x16x32_f16(A1H, b1l, C, 0, 0, 0);     \
    } while (0)

// ---------- conv1 node MLP via split-fp16 MFMA; writes interleaved h1[n][64] ----------
__global__ void node1_kernel(const float* __restrict__ xs,
                             const __half* __restrict__ pk1Ah, const __half* __restrict__ pk1Al,
                             const float* __restrict__ b1a,
                             const __half* __restrict__ pk1Bh, const __half* __restrict__ pk1Bl,
                             const float* __restrict__ b1b,
                             __half* __restrict__ h1) {
    __shared__ float hbuf[4][16][68];
    int wv = threadIdx.x >> 6;
    int lane = threadIdx.x & 63;
    int gwave = blockIdx.x * 4 + wv;
    bool active = gwave < (N_NODES / 16);
    int base = active ? gwave * 16 : 0;
    int m = lane & 15, q = lane >> 4;
    const _Float16* pAh = (const _Float16*)pk1Ah;
    const _Float16* pAl = (const _Float16*)pk1Al;
    const _Float16* pBh = (const _Float16*)pk1Bh;
    const _Float16* pBl = (const _Float16*)pk1Bl;

    f16x8 ah, al;
    split8(xs + (size_t)(base + m) * 32 + q * 8, ah, al);
#pragma unroll
    for (int t = 0; t < 4; ++t) {
        f32x4 c = {0.f, 0.f, 0.f, 0.f};
        f16x8 bh = *(const f16x8*)(pAh + (t * 64 + lane) * 8);
        f16x8 bl = *(const f16x8*)(pAl + (t * 64 + lane) * 8);
        c = __builtin_amdgcn_mfma_f32_16x16x32_f16(ah, bh, c, 0, 0, 0);
        c = __builtin_amdgcn_mfma_f32_16x16x32_f16(al, bh, c, 0, 0, 0);
        c = __builtin_amdgcn_mfma_f32_16x16x32_f16(ah, bl, c, 0, 0, 0);
        float bias = b1a[t * 16 + m];
#pragma unroll
        for (int r = 0; r < 4; ++r)
            hbuf[wv][q * 4 + r][t * 16 + m] = fmaxf(c[r] + bias, 0.f);
    }
    __syncthreads();
    f16x8 a0h, a0l, a1h, a1l;
    split8(&hbuf[wv][m][q * 8], a0h, a0l);
    split8(&hbuf[wv][m][32 + q * 8], a1h, a1l);
    float tmp[4][4];
#pragma unroll
    for (int t = 0; t < 4; ++t) {
        f32x4 c = {0.f, 0.f, 0.f, 0.f};
        TILE3(c, a0h, a0l, a1h, a1l, pBh, pBl, t);
        float bias = b1b[t * 16 + m];
#pragma unroll
        for (int r = 0; r < 4; ++r)
            tmp[t][r] = fmaxf(c[r] + bias, 0.f);
    }
    __syncthreads();
#pragma unroll
    for (int t = 0; t < 4; ++t)
#pragma unroll
        for (int r = 0; r < 4; ++r)
            hbuf[wv][q * 4 + r][t * 16 + m] = tmp[t][r];
    __syncthreads();
    if (active) {
        int nn = lane >> 2, part = lane & 3;
        f16x8 vlo, vhi;
        const float* rlo = &hbuf[wv][nn][part * 8];
        const float* rhi = &hbuf[wv][nn][32 + part * 8];
#pragma unroll
        for (int j = 0; j < 8; ++j) {
            vlo[j] = (_Float16)rlo[j];
            vhi[j] = (_Float16)rhi[j];
        }
        *(f16x8*)(h1 + (size_t)(base + nn) * 64 + part * 8) = vlo;
        *(f16x8*)(h1 + (size_t)(base + nn) * 64 + 32 + part * 8) = vhi;
    }
}

// ---------- conv2 aggregation, packed-pair form ----------
__global__ void aggphase2_kernel(const __half* __restrict__ h1,
                                 const int* __restrict__ starts,
                                 const int* __restrict__ deg,
                                 const unsigned* __restrict__ ep4,
                                 const float* __restrict__ ew,
                                 const float* __restrict__ eb,
                                 float* __restrict__ htot) {
    int n = blockIdx.x * (blockDim.x >> 6) + (threadIdx.x >> 6);
    int lane = threadIdx.x & 63;
    if (n >= N_NODES) return;
    int half = lane >> 5;                // which edge of the pair
    int l = lane & 31;                   // feature-pair index
    int s0 = starts[n], dg = deg[n];
    const unsigned* ep = ep4 + s0;
    const unsigned* h1u = (const unsigned*)h1;   // row stride 32 uints
    float2 w2 = *(const float2*)(ew + 2 * l);
    float2 b2 = *(const float2*)(eb + 2 * l);
    float acc0 = 0.f, acc1 = 0.f;
#define EDGE2(P, V) do {                                                   \
        float a_ = UNPACK_ATTR(P);                                         \
        __half2 hv_ = *(const __half2*)&(V);                               \
        float2 vf_ = __half22float2(hv_);                                  \
        acc0 += fmaxf(vf_.x + a_ * w2.x + b2.x, 0.f);                      \
        acc1 += fmaxf(vf_.y + a_ * w2.y + b2.y, 0.f);                      \
    } while (0)
    int j = 0;
    for (; j + 8 <= dg; j += 8) {
        unsigned p0 = ep[j + 0 + half], p1 = ep[j + 2 + half];
        unsigned p2 = ep[j + 4 + half], p3 = ep[j + 6 + half];
        unsigned v0 = h1u[(size_t)(p0 >> 16) * 32 + l];
        unsigned v1 = h1u[(size_t)(p1 >> 16) * 32 + l];
        unsigned v2 = h1u[(size_t)(p2 >> 16) * 32 + l];
        unsigned v3 = h1u[(size_t)(p3 >> 16) * 32 + l];
        EDGE2(p0, v0); EDGE2(p1, v1); EDGE2(p2, v2); EDGE2(p3, v3);
    }
    for (; j + 2 <= dg; j += 2) {
        unsigned p = ep[j + half];
        unsigned v = h1u[(size_t)(p >> 16) * 32 + l];
        EDGE2(p, v);
    }
    if (j < dg && half == 0) {
        unsigned p = ep[j];
        unsigned v = h1u[(size_t)(p >> 16) * 32 + l];
        EDGE2(p, v);
    }
#undef EDGE2
    acc0 += __shfl_xor(acc0, 32, 64);
    acc1 += __shfl_xor(acc1, 32, 64);
    if (half == 0) {
        unsigned sv = h1u[(size_t)n * 32 + l];
        float2 sf = __half22float2(*(const __half2*)&sv);
        f32x2 o;
        o[0] = sf.x + acc0;
        o[1] = sf.y + acc1;
        __builtin_nontemporal_store(o, (f32x2*)(htot + (size_t)n * 64 + 2 * l));
    }
}

// ---------- node2 via split-fp16 MFMA; writes pi and accumulates te ----------
__global__ void node2_kernel(const float* __restrict__ htot,
                             const __half* __restrict__ pkAh, const __half* __restrict__ pkAl,
                             const float* __restrict__ b2a,
                             const __half* __restrict__ pkBh, const __half* __restrict__ pkBl,
                             const float* __restrict__ b2b,
                             const __half* __restrict__ pkRh, const __half* __restrict__ pkRl,
                             const float* __restrict__ br1,
                             const float* __restrict__ wr2,
                             const float* __restrict__ br2,
                             const int* __restrict__ term,
                             const int* __restrict__ batch,
                             const float* __restrict__ ccost,
                             float* __restrict__ pi,
                             float* __restrict__ te) {
    __shared__ float hbuf[4][16][68];
    int wv = threadIdx.x >> 6;
    int lane = threadIdx.x & 63;
    int gwave = blockIdx.x * 4 + wv;
    bool active = gwave < (N_NODES / 16);
    int base = active ? gwave * 16 : 0;
    int m = lane & 15, q = lane >> 4;
    const _Float16* pAh = (const _Float16*)pkAh;
    const _Float16* pAl = (const _Float16*)pkAl;
    const _Float16* pBh = (const _Float16*)pkBh;
    const _Float16* pBl = (const _Float16*)pkBl;
    const _Float16* pRh = (const _Float16*)pkRh;
    const _Float16* pRl = (const _Float16*)pkRl;

    f16x8 a0h, a0l, a1h, a1l;
    {
        const float* hrow = htot + (size_t)(base + m) * 64;
        split8(hrow + q * 8, a0h, a0l);
        split8(hrow + 32 + q * 8, a1h, a1l);
    }
#pragma unroll
    for (int t = 0; t < 4; ++t) {
        f32x4 c = {0.f, 0.f, 0.f, 0.f};
        TILE3(c, a0h, a0l, a1h, a1l, pAh, pAl, t);
        float bias = b2a[t * 16 + m];
#pragma unroll
        for (int r = 0; r < 4; ++r)
            hbuf[wv][q * 4 + r][t * 16 + m] = fmaxf(c[r] + bias, 0.f);
    }
    __syncthreads();
    split8(&hbuf[wv][m][q * 8], a0h, a0l);
    split8(&hbuf[wv][m][32 + q * 8], a1h, a1l);
    float tmp[4][4];
#pragma unroll
    for (int t = 0; t < 4; ++t) {
        f32x4 c = {0.f, 0.f, 0.f, 0.f};
        TILE3(c, a0h, a0l, a1h, a1l, pBh, pBl, t);
        float bias = b2b[t * 16 + m];
#pragma unroll
        for (int r = 0; r < 4; ++r)
            tmp[t][r] = fmaxf(c[r] + bias, 0.f);
    }
    __syncthreads();
#pragma unroll
    for (int t = 0; t < 4; ++t)
#pragma unroll
        for (int r = 0; r < 4; ++r)
            hbuf[wv][q * 4 + r][t * 16 + m] = tmp[t][r];
    __syncthreads();
    split8(&hbuf[wv][m][q * 8], a0h, a0l);
    split8(&hbuf[wv][m][32 + q * 8], a1h, a1l);
    float partial[4] = {0.f, 0.f, 0.f, 0.f};
#pragma unroll
    for (int t = 0; t < 2; ++t) {
        f32x4 c = {0.f, 0.f, 0.f, 0.f};
        TILE3(c, a0h, a0l, a1h, a1l, pRh, pRl, t);
        float bias = br1[t * 16 + m];
        float wv2 = wr2[t * 16 + m];
#pragma unroll
        for (int r = 0; r < 4; ++r)
            partial[r] += fmaxf(c[r] + bias, 0.f) * wv2;
    }
#pragma unroll
    for (int off = 1; off < 16; off <<= 1) {
        partial[0] += __shfl_xor(partial[0], off, 64);
        partial[1] += __shfl_xor(partial[1], off, 64);
        partial[2] += __shfl_xor(partial[2], off, 64);
        partial[3] += __shfl_xor(partial[3], off, 64);
    }
    if (active && m == 0) {
#pragma unroll
        for (int r = 0; r < 4; ++r) {
            int n = base + q * 4 + r;
            float z = partial[r] + br2[0];
            float sig = 1.f / (1.f + expf(-z));
            float pv = sig * (1.f - (float)term[n]);
            pi[n] = pv;
            float contrib = pv * ccost[n];
            if (contrib != 0.f) atomicAdd(&te[batch[n]], contrib);
        }
    }
}

__global__ void final_kernel(const float* __restrict__ pi,
                             const int* __restrict__ batch,
                             const float* __restrict__ Btot,
                             const float* __restrict__ te,
                             float* __restrict__ out) {
    int n = blockIdx.x * blockDim.x + threadIdx.x;
    if (n >= N_NODES) return;
    int b = batch[n];
    float ratio = fminf(Btot[b] / (te[b] + 1e-12f), 1.f);
    out[n] = pi[n] * ratio;
}

extern "C" void kernel_launch(void* const* d_in, const int* in_sizes, int n_in,
                              void* d_out, int out_size, void* d_ws, size_t ws_size,
                              hipStream_t stream) {
    const float* x     = (const float*)d_in[0];
    const int*   ei    = (const int*)d_in[1];
    const float* ea    = (const float*)d_in[2];
    const int*   batch = (const int*)d_in[3];
    const float* Btot  = (const float*)d_in[4];
    const int*   term  = (const int*)d_in[5];
    const float* ccost = (const float*)d_in[6];
    const float* e1w   = (const float*)d_in[7];
    const float* e1b   = (const float*)d_in[8];
    const float* w1a   = (const float*)d_in[9];
    const float* b1a   = (const float*)d_in[10];
    const float* w1b   = (const float*)d_in[11];
    const float* b1b   = (const float*)d_in[12];
    const float* e2w   = (const float*)d_in[13];
    const float* e2b   = (const float*)d_in[14];
    const float* w2a   = (const float*)d_in[15];
    const float* b2a   = (const float*)d_in[16];
    const float* w2b   = (const float*)d_in[17];
    const float* b2b   = (const float*)d_in[18];
    const float* wr1   = (const float*)d_in[19];
    const float* br1   = (const float*)d_in[20];
    const float* wr2   = (const float*)d_in[21];
    const float* br2   = (const float*)d_in[22];

    char* p = (char*)d_ws;
    int*      bnext  = (int*)p;      p += sizeof(int)      * 1024;      // zeroed (782 used)
    float*    te     = (float*)p;    p += sizeof(float)    * N_GRAPHS;  // zeroed
    int*      starts = (int*)p;      p += sizeof(int)      * N_NODES;
    int*      deg    = (int*)p;      p += sizeof(int)      * N_NODES;
    p = (char*)(((size_t)p + 15) & ~(size_t)15);
    uint2*    ebuk   = (uint2*)p;    p += sizeof(uint2)    * (size_t)N_FBUK * FCAP;
    unsigned* ep4    = (unsigned*)p; p += sizeof(unsigned) * (size_t)N_FBUK * FCAP;
    __half*   h1     = (__half*)p;   p += sizeof(__half)   * (size_t)N_NODES * 64;
    float*    htot   = (float*)p;    p += sizeof(float)    * (size_t)N_NODES * 64;
    float*    xs     = (float*)p;    p += sizeof(float)    * (size_t)N_NODES * 32;
    float*    pi     = (float*)p;    p += sizeof(float)    * N_NODES;
    __half*   pk1Ah  = (__half*)p;   p += sizeof(__half)   * 2048;
    __half*   pk1Al  = (__half*)p;   p += sizeof(__half)   * 2048;
    __half*   pk1Bh  = (__half*)p;   p += sizeof(__half)   * 4096;
    __half*   pk1Bl  = (__half*)p;   p += sizeof(__half)   * 4096;
    __half*   pkAh   = (__half*)p;   p += sizeof(__half)   * 4096;
    __half*   pkAl   = (__half*)p;   p += sizeof(__half)   * 4096;
    __half*   pkBh   = (__half*)p;   p += sizeof(__half)   * 4096;
    __half*   pkBl   = (__half*)p;   p += sizeof(__half)   * 4096;
    __half*   pkRh   = (__half*)p;   p += sizeof(__half)   * 2048;
    __half*   pkRl   = (__half*)p;   p += sizeof(__half)   * 2048;
    float*    out    = (float*)d_out;

    hipMemsetAsync(d_ws, 0, sizeof(int) * 1024 + sizeof(float) * N_GRAPHS, stream);

    bucket_scatter<<<1 + N_SBLK, 512, 0, stream>>>(ei, ea, bnext, ebuk,
                                                   w1a, w1b, w2a, w2b, wr1,
                                                   pk1Ah, pk1Al, pk1Bh, pk1Bl,
                                                   pkAh, pkAl, pkBh, pkBl, pkRh, pkRl);
    bucket_fine<<<N_FBUK, 512, 0, stream>>>(ebuk, bnext, ep4, starts, deg);
    agg1_kernel<<<(N_NODES + 3) / 4, 256, 0, stream>>>(x, starts, deg, ep4, e1w, e1b, xs);
    node1_kernel<<<(N_NODES / 16 + 3) / 4, 256, 0, stream>>>(xs, pk1Ah, pk1Al, b1a,
                                                             pk1Bh, pk1Bl, b1b, h1);
    aggphase2_kernel<<<(N_NODES + 3) / 4, 256, 0, stream>>>(h1, starts, deg, ep4,
                                                            e2w, e2b, htot);
    node2_kernel<<<(N_NODES / 16 + 3) / 4, 256, 0, stream>>>(htot,
                                                             pkAh, pkAl, b2a,
                                                             pkBh, pkBl, b2b,
                                                             pkRh, pkRl, br1,
                                                             wr2, br2, term,
                                                             batch, ccost, pi, te);
    final_kernel<<<(N_NODES + 255) / 256, 256, 0, stream>>>(pi, batch, Btot, te, out);
}

// Round 10
// 224.201 us; speedup vs baseline: 1.1354x; 1.0539x over previous
//
#include <hip/hip_runtime.h>
#include <hip/hip_fp16.h>
#include <math.h>

#define N_NODES 50000
#define N_EDGES 1600000
#define N_GRAPHS 512
#define F_IN 9
#define H 64
#define EPB 4096
#define N_SBLK ((N_EDGES + EPB - 1) / EPB)   // 391
// 64-node fine buckets: 782 blocks (~3/CU) for sort parallelism
#define BUCKET_NODES 64
#define N_FBUK ((N_NODES + BUCKET_NODES - 1) / BUCKET_NODES)   // 782
#define FCAP 2816                            // mean 2048, sd ~45 -> +17 sd

typedef _Float16 f16x8 __attribute__((ext_vector_type(8)));
typedef float f32x4 __attribute__((ext_vector_type(4)));
typedef float f32x2 __attribute__((ext_vector_type(2)));

__device__ __forceinline__ void pack_weights_body(
        const float* __restrict__ w1a, const float* __restrict__ w1b,
        const float* __restrict__ w2a, const float* __restrict__ w2b,
        const float* __restrict__ wr1,
        __half* __restrict__ pk1Ah, __half* __restrict__ pk1Al,
        __half* __restrict__ pk1Bh, __half* __restrict__ pk1Bl,
        __half* __restrict__ pkAh, __half* __restrict__ pkAl,
        __half* __restrict__ pkBh, __half* __restrict__ pkBl,
        __half* __restrict__ pkRh, __half* __restrict__ pkRl) {
    int t = threadIdx.x;
    for (int i = t; i < 2048; i += 512) {      // w1a: [64][9], K=32 zero-pad
        int j = i & 7, l = (i >> 3) & 63, tt = i >> 9;
        int q = l >> 4, n = l & 15;
        int k = q * 8 + j;
        float v = (k < F_IN) ? w1a[(tt * 16 + n) * F_IN + k] : 0.f;
        __half h = __float2half(v);
        pk1Ah[i] = h; pk1Al[i] = __float2half(v - __half2float(h));
    }
    for (int i = t; i < 4096; i += 512) {
        int j = i & 7, l = (i >> 3) & 63, c = (i >> 9) & 1, tt = i >> 10;
        int q = l >> 4, n = l & 15;
        int src = (tt * 16 + n) * H + c * 32 + q * 8 + j;
        float v1 = w1b[src], wa = w2a[src], wb = w2b[src];
        __half h1 = __float2half(v1), ah = __float2half(wa), bh = __float2half(wb);
        pk1Bh[i] = h1; pk1Bl[i] = __float2half(v1 - __half2float(h1));
        pkAh[i] = ah; pkAl[i] = __float2half(wa - __half2float(ah));
        pkBh[i] = bh; pkBl[i] = __float2half(wb - __half2float(bh));
    }
    for (int i = t; i < 2048; i += 512) {
        int j = i & 7, l = (i >> 3) & 63, c = (i >> 9) & 1, tt = i >> 10;
        int q = l >> 4, n = l & 15;
        float wr = wr1[(tt * 16 + n) * H + c * 32 + q * 8 + j];
        __half rh = __float2half(wr);
        pkRh[i] = rh; pkRl[i] = __float2half(wr - __half2float(rh));
    }
}

// ---------- bucket scatter (fixed-capacity buckets); block 0 packs weights ----------
// rk packing: b(10b)<<19 | dl(6b)<<13 | r(13b)
__global__ void __launch_bounds__(512)
bucket_scatter(const int* __restrict__ ei,
               const float* __restrict__ ea,
               int* __restrict__ bnext,
               uint2* __restrict__ ebuk,
               const float* __restrict__ w1a,
               const float* __restrict__ w1b,
               const float* __restrict__ w2a,
               const float* __restrict__ w2b,
               const float* __restrict__ wr1,
               __half* pk1Ah, __half* pk1Al,
               __half* pk1Bh, __half* pk1Bl,
               __half* pkAh, __half* pkAl,
               __half* pkBh, __half* pkBl,
               __half* pkRh, __half* pkRl) {
    if (blockIdx.x == 0) {
        pack_weights_body(w1a, w1b, w2a, w2b, wr1, pk1Ah, pk1Al, pk1Bh, pk1Bl,
                          pkAh, pkAl, pkBh, pkBl, pkRh, pkRl);
        return;
    }
    __shared__ int cnt[N_FBUK];
    __shared__ int gbase[N_FBUK];
    for (int i = threadIdx.x; i < N_FBUK; i += 512) cnt[i] = 0;
    __syncthreads();
    int base = (blockIdx.x - 1) * EPB;
    int rk[8];
    unsigned pay[8];
#pragma unroll
    for (int j = 0; j < 8; ++j) {
        int e = base + j * 512 + threadIdx.x;
        rk[j] = -1;
        if (e < N_EDGES) {
            int d = ei[N_EDGES + e];
            int s = ei[e];
            float a = ea[e];
            pay[j] = ((unsigned)s << 16) |
                     (unsigned)__half_as_ushort(__float2half(a));
            int b = d >> 6;
            int r = atomicAdd(&cnt[b], 1);
            rk[j] = (b << 19) | ((d & 63) << 13) | r;
        }
    }
    __syncthreads();
    for (int i = threadIdx.x; i < N_FBUK; i += 512)
        gbase[i] = cnt[i] ? atomicAdd(&bnext[i], cnt[i]) : 0;
    __syncthreads();
#pragma unroll
    for (int j = 0; j < 8; ++j) {
        if (rk[j] < 0) continue;
        int b = rk[j] >> 19, dl = (rk[j] >> 13) & 63, r = rk[j] & 8191;
        int slot = gbase[b] + r;
        if (slot >= FCAP) continue;
        ebuk[(size_t)b * FCAP + slot] = make_uint2(pay[j], (unsigned)dl);
    }
}

#define UNPACK_ATTR(P) __half2float(__ushort_as_half((unsigned short)((P) & 0xffffu)))

// ---------- per-bucket fine sort -> node CSR + ep4 + FUSED conv1 aggregation ----------
// 64-node buckets, 782 blocks (~3/CU, 24 waves/CU). After the LDS sort, each of
// the 8 waves aggregates conv1 for 8 nodes straight from LDS (no ep4 re-read).
__global__ void __launch_bounds__(512)
bucket_fine(const uint2* __restrict__ ebuk,
            const int* __restrict__ bnext,
            unsigned* __restrict__ ep4,
            int* __restrict__ starts, int* __restrict__ deg,
            const float* __restrict__ x,
            const float* __restrict__ e1w,
            const float* __restrict__ e1b,
            float* __restrict__ xs) {
    __shared__ unsigned sorted[FCAP];
    __shared__ int cntN[BUCKET_NODES], offN[BUCKET_NODES], nxtN[BUCKET_NODES];
    int b = blockIdx.x;
    int base = b * FCAP;
    int count = bnext[b];
    if (count > FCAP) count = FCAP;
    int tid = threadIdx.x;
    if (tid < BUCKET_NODES) cntN[tid] = 0;
    __syncthreads();
    uint2 ev[6];                                // FCAP/512 = 5.5 -> 6
#pragma unroll
    for (int k = 0; k < 6; ++k) {
        int i = tid + k * 512;
        ev[k] = (i < count) ? ebuk[base + i] : make_uint2(0u, 0xFFFFFFFFu);
    }
#pragma unroll
    for (int k = 0; k < 6; ++k)
        if (ev[k].y < (unsigned)BUCKET_NODES) atomicAdd(&cntN[ev[k].y], 1);
    __syncthreads();
    if (tid < 64) {                     // wave 0: 64-entry scan in one wave
        int v = cntN[tid];
        int incl = v;
#pragma unroll
        for (int off = 1; off < 64; off <<= 1) {
            int t = __shfl_up(incl, off, 64);
            if (tid >= off) incl += t;
        }
        int excl = incl - v;
        offN[tid] = excl;
        nxtN[tid] = 0;
        int n = (b << 6) + tid;
        if (n < N_NODES) { starts[n] = base + excl; deg[n] = v; }
    }
    __syncthreads();
#pragma unroll
    for (int k = 0; k < 6; ++k) {
        if (ev[k].y < (unsigned)BUCKET_NODES) {
            int r = atomicAdd(&nxtN[ev[k].y], 1);
            sorted[offN[ev[k].y] + r] = ev[k].x;
        }
    }
    __syncthreads();
    // write node-sorted edges for conv2's aggregation pass
    for (int i = tid; i < count; i += 512)
        ep4[base + i] = sorted[i];

    // ---- fused conv1 aggregation from LDS (wave w -> nodes w*8 .. w*8+7) ----
    int lane = tid & 63, wid = tid >> 6;
    int slot = lane >> 4;                 // 0..3 edge-ILP slot
    int f = lane & 15;
    bool act = f < F_IN;
    float wf = act ? e1w[f] : 0.f;
    float bf = act ? e1b[f] : 0.f;
#pragma unroll
    for (int i = 0; i < 8; ++i) {
        int nloc = wid * 8 + i;           // wave-uniform
        int n = (b << 6) + nloc;
        if (n >= N_NODES) break;
        int off = offN[nloc];
        int dgN = cntN[nloc];
        float acc = 0.f;
        int j = slot;
        for (; j + 12 < dgN; j += 16) {
            unsigned pa = sorted[off + j];
            unsigned pb = sorted[off + j + 4];
            unsigned pc = sorted[off + j + 8];
            unsigned pd = sorted[off + j + 12];
            float xa_ = act ? x[(pa >> 16) * F_IN + f] : 0.f;
            float xb_ = act ? x[(pb >> 16) * F_IN + f] : 0.f;
            float xc_ = act ? x[(pc >> 16) * F_IN + f] : 0.f;
            float xd_ = act ? x[(pd >> 16) * F_IN + f] : 0.f;
            if (act) {
                acc += fmaxf(xa_ + UNPACK_ATTR(pa) * wf + bf, 0.f)
                     + fmaxf(xb_ + UNPACK_ATTR(pb) * wf + bf, 0.f)
                     + fmaxf(xc_ + UNPACK_ATTR(pc) * wf + bf, 0.f)
                     + fmaxf(xd_ + UNPACK_ATTR(pd) * wf + bf, 0.f);
            }
        }
        for (; j < dgN; j += 4) {
            unsigned p = sorted[off + j];
            float xv = act ? x[(p >> 16) * F_IN + f] : 0.f;
            float m = xv + UNPACK_ATTR(p) * wf + bf;
            acc += act ? fmaxf(m, 0.f) : 0.f;
        }
        acc += __shfl_xor(acc, 16, 64);
        acc += __shfl_xor(acc, 32, 64);
        if (lane < 32) {
            float o = (lane < F_IN) ? x[n * F_IN + lane] + acc : 0.f;
            __builtin_nontemporal_store(o, xs + n * 32 + lane);
        }
    }
}

__device__ __forceinline__ void split8(const float* __restrict__ v,
                                       f16x8& hi, f16x8& lo) {
#pragma unroll
    for (int j = 0; j < 8; ++j) {
        _Float16 h = (_Float16)v[j];
        hi[j] = h;
        lo[j] = (_Float16)(v[j] - (float)h);
    }
}

#define TILE3(C, A0H, A0L, A1H, A1L, PH, PL, T) do {                          \
        f16x8 b0h = *(const f16x8*)((PH) + (((T) * 2 + 0) * 64 + lane) * 8);  \
        f16x8 b0l = *(const f16x8*)((PL) + (((T) * 2 + 0) * 64 + lane) * 8);  \
        f16x8 b1h = *(const f16x8*)((PH) + (((T) * 2 + 1) * 64 + lane) * 8);  \
        f16x8 b1l = *(const f16x8*)((PL) + (((T) * 2 + 1) * 64 + lane) * 8);  \
        C = __builtin_amdgcn_mfma_f32_16x16x32_f16(A0H, b0h, C, 0, 0, 0);     \
        C = __builtin_amdgcn_mfma_f32_16x16x32_f16(A0L, b0h, C, 0, 0, 0);     \
        C = __builtin_amdgcn_mfma_f32_16x16x32_f16(A0H, b0l, C, 0, 0, 0);     \
        C = __builtin_amdgcn_mfma_f32_16x16x32_f16(A1H, b1h, C, 0, 0, 0);     \
        C = __builtin_amdgcn_mfma_f32_16x16x32_f16(A1L, b1h, C, 0, 0, 0);     \
        C = __builtin_amdgcn_mfma_f32_16x16x32_f16(A1H, b1l, C, 0, 0, 0);     \
    } while (0)

// ---------- conv1 node MLP via split-fp16 MFMA; writes interleaved h1[n][64] ----------
__global__ void node1_kernel(const float* __restrict__ xs,
                             const __half* __restrict__ pk1Ah, const __half* __restrict__ pk1Al,
                             const float* __restrict__ b1a,
                             const __half* __restrict__ pk1Bh, const __half* __restrict__ pk1Bl,
                             const float* __restrict__ b1b,
                             __half* __restrict__ h1) {
    __shared__ float hbuf[4][16][68];
    int wv = threadIdx.x >> 6;
    int lane = threadIdx.x & 63;
    int gwave = blockIdx.x * 4 + wv;
    bool active = gwave < (N_NODES / 16);
    int base = active ? gwave * 16 : 0;
    int m = lane & 15, q = lane >> 4;
    const _Float16* pAh = (const _Float16*)pk1Ah;
    const _Float16* pAl = (const _Float16*)pk1Al;
    const _Float16* pBh = (const _Float16*)pk1Bh;
    const _Float16* pBl = (const _Float16*)pk1Bl;

    f16x8 ah, al;
    split8(xs + (size_t)(base + m) * 32 + q * 8, ah, al);
#pragma unroll
    for (int t = 0; t < 4; ++t) {
        f32x4 c = {0.f, 0.f, 0.f, 0.f};
        f16x8 bh = *(const f16x8*)(pAh + (t * 64 + lane) * 8);
        f16x8 bl = *(const f16x8*)(pAl + (t * 64 + lane) * 8);
        c = __builtin_amdgcn_mfma_f32_16x16x32_f16(ah, bh, c, 0, 0, 0);
        c = __builtin_amdgcn_mfma_f32_16x16x32_f16(al, bh, c, 0, 0, 0);
        c = __builtin_amdgcn_mfma_f32_16x16x32_f16(ah, bl, c, 0, 0, 0);
        float bias = b1a[t * 16 + m];
#pragma unroll
        for (int r = 0; r < 4; ++r)
            hbuf[wv][q * 4 + r][t * 16 + m] = fmaxf(c[r] + bias, 0.f);
    }
    __syncthreads();
    f16x8 a0h, a0l, a1h, a1l;
    split8(&hbuf[wv][m][q * 8], a0h, a0l);
    split8(&hbuf[wv][m][32 + q * 8], a1h, a1l);
    float tmp[4][4];
#pragma unroll
    for (int t = 0; t < 4; ++t) {
        f32x4 c = {0.f, 0.f, 0.f, 0.f};
        TILE3(c, a0h, a0l, a1h, a1l, pBh, pBl, t);
        float bias = b1b[t * 16 + m];
#pragma unroll
        for (int r = 0; r < 4; ++r)
            tmp[t][r] = fmaxf(c[r] + bias, 0.f);
    }
    __syncthreads();
#pragma unroll
    for (int t = 0; t < 4; ++t)
#pragma unroll
        for (int r = 0; r < 4; ++r)
            hbuf[wv][q * 4 + r][t * 16 + m] = tmp[t][r];
    __syncthreads();
    if (active) {
        int nn = lane >> 2, part = lane & 3;
        f16x8 vlo, vhi;
        const float* rlo = &hbuf[wv][nn][part * 8];
        const float* rhi = &hbuf[wv][nn][32 + part * 8];
#pragma unroll
        for (int j = 0; j < 8; ++j) {
            vlo[j] = (_Float16)rlo[j];
            vhi[j] = (_Float16)rhi[j];
        }
        *(f16x8*)(h1 + (size_t)(base + nn) * 64 + part * 8) = vlo;
        *(f16x8*)(h1 + (size_t)(base + nn) * 64 + 32 + part * 8) = vhi;
    }
}

// ---------- conv2 aggregation, packed-pair form ----------
__global__ void aggphase2_kernel(const __half* __restrict__ h1,
                                 const int* __restrict__ starts,
                                 const int* __restrict__ deg,
                                 const unsigned* __restrict__ ep4,
                                 const float* __restrict__ ew,
                                 const float* __restrict__ eb,
                                 float* __restrict__ htot) {
    int n = blockIdx.x * (blockDim.x >> 6) + (threadIdx.x >> 6);
    int lane = threadIdx.x & 63;
    if (n >= N_NODES) return;
    int half = lane >> 5;                // which edge of the pair
    int l = lane & 31;                   // feature-pair index
    int s0 = starts[n], dg = deg[n];
    const unsigned* ep = ep4 + s0;
    const unsigned* h1u = (const unsigned*)h1;   // row stride 32 uints
    float2 w2 = *(const float2*)(ew + 2 * l);
    float2 b2 = *(const float2*)(eb + 2 * l);
    float acc0 = 0.f, acc1 = 0.f;
#define EDGE2(P, V) do {                                                   \
        float a_ = UNPACK_ATTR(P);                                         \
        __half2 hv_ = *(const __half2*)&(V);                               \
        float2 vf_ = __half22float2(hv_);                                  \
        acc0 += fmaxf(vf_.x + a_ * w2.x + b2.x, 0.f);                      \
        acc1 += fmaxf(vf_.y + a_ * w2.y + b2.y, 0.f);                      \
    } while (0)
    int j = 0;
    for (; j + 8 <= dg; j += 8) {
        unsigned p0 = ep[j + 0 + half], p1 = ep[j + 2 + half];
        unsigned p2 = ep[j + 4 + half], p3 = ep[j + 6 + half];
        unsigned v0 = h1u[(size_t)(p0 >> 16) * 32 + l];
        unsigned v1 = h1u[(size_t)(p1 >> 16) * 32 + l];
        unsigned v2 = h1u[(size_t)(p2 >> 16) * 32 + l];
        unsigned v3 = h1u[(size_t)(p3 >> 16) * 32 + l];
        EDGE2(p0, v0); EDGE2(p1, v1); EDGE2(p2, v2); EDGE2(p3, v3);
    }
    for (; j + 2 <= dg; j += 2) {
        unsigned p = ep[j + half];
        unsigned v = h1u[(size_t)(p >> 16) * 32 + l];
        EDGE2(p, v);
    }
    if (j < dg && half == 0) {
        unsigned p = ep[j];
        unsigned v = h1u[(size_t)(p >> 16) * 32 + l];
        EDGE2(p, v);
    }
#undef EDGE2
    acc0 += __shfl_xor(acc0, 32, 64);
    acc1 += __shfl_xor(acc1, 32, 64);
    if (half == 0) {
        unsigned sv = h1u[(size_t)n * 32 + l];
        float2 sf = __half22float2(*(const __half2*)&sv);
        f32x2 o;
        o[0] = sf.x + acc0;
        o[1] = sf.y + acc1;
        __builtin_nontemporal_store(o, (f32x2*)(htot + (size_t)n * 64 + 2 * l));
    }
}

// ---------- node2 via split-fp16 MFMA; writes pi and accumulates te ----------
__global__ void node2_kernel(const float* __restrict__ htot,
                             const __half* __restrict__ pkAh, const __half* __restrict__ pkAl,
                             const float* __restrict__ b2a,
                             const __half* __restrict__ pkBh, const __half* __restrict__ pkBl,
                             const float* __restrict__ b2b,
                             const __half* __restrict__ pkRh, const __half* __restrict__ pkRl,
                             const float* __restrict__ br1,
                             const float* __restrict__ wr2,
                             const float* __restrict__ br2,
                             const int* __restrict__ term,
                             const int* __restrict__ batch,
                             const float* __restrict__ ccost,
                             float* __restrict__ pi,
                             float* __restrict__ te) {
    __shared__ float hbuf[4][16][68];
    int wv = threadIdx.x >> 6;
    int lane = threadIdx.x & 63;
    int gwave = blockIdx.x * 4 + wv;
    bool active = gwave < (N_NODES / 16);
    int base = active ? gwave * 16 : 0;
    int m = lane & 15, q = lane >> 4;
    const _Float16* pAh = (const _Float16*)pkAh;
    const _Float16* pAl = (const _Float16*)pkAl;
    const _Float16* pBh = (const _Float16*)pkBh;
    const _Float16* pBl = (const _Float16*)pkBl;
    const _Float16* pRh = (const _Float16*)pkRh;
    const _Float16* pRl = (const _Float16*)pkRl;

    f16x8 a0h, a0l, a1h, a1l;
    {
        const float* hrow = htot + (size_t)(base + m) * 64;
        split8(hrow + q * 8, a0h, a0l);
        split8(hrow + 32 + q * 8, a1h, a1l);
    }
#pragma unroll
    for (int t = 0; t < 4; ++t) {
        f32x4 c = {0.f, 0.f, 0.f, 0.f};
        TILE3(c, a0h, a0l, a1h, a1l, pAh, pAl, t);
        float bias = b2a[t * 16 + m];
#pragma unroll
        for (int r = 0; r < 4; ++r)
            hbuf[wv][q * 4 + r][t * 16 + m] = fmaxf(c[r] + bias, 0.f);
    }
    __syncthreads();
    split8(&hbuf[wv][m][q * 8], a0h, a0l);
    split8(&hbuf[wv][m][32 + q * 8], a1h, a1l);
    float tmp[4][4];
#pragma unroll
    for (int t = 0; t < 4; ++t) {
        f32x4 c = {0.f, 0.f, 0.f, 0.f};
        TILE3(c, a0h, a0l, a1h, a1l, pBh, pBl, t);
        float bias = b2b[t * 16 + m];
#pragma unroll
        for (int r = 0; r < 4; ++r)
            tmp[t][r] = fmaxf(c[r] + bias, 0.f);
    }
    __syncthreads();
#pragma unroll
    for (int t = 0; t < 4; ++t)
#pragma unroll
        for (int r = 0; r < 4; ++r)
            hbuf[wv][q * 4 + r][t * 16 + m] = tmp[t][r];
    __syncthreads();
    split8(&hbuf[wv][m][q * 8], a0h, a0l);
    split8(&hbuf[wv][m][32 + q * 8], a1h, a1l);
    float partial[4] = {0.f, 0.f, 0.f, 0.f};
#pragma unroll
    for (int t = 0; t < 2; ++t) {
        f32x4 c = {0.f, 0.f, 0.f, 0.f};
        TILE3(c, a0h, a0l, a1h, a1l, pRh, pRl, t);
        float bias = br1[t * 16 + m];
        float wv2 = wr2[t * 16 + m];
#pragma unroll
        for (int r = 0; r < 4; ++r)
            partial[r] += fmaxf(c[r] + bias, 0.f) * wv2;
    }
#pragma unroll
    for (int off = 1; off < 16; off <<= 1) {
        partial[0] += __shfl_xor(partial[0], off, 64);
        partial[1] += __shfl_xor(partial[1], off, 64);
        partial[2] += __shfl_xor(partial[2], off, 64);
        partial[3] += __shfl_xor(partial[3], off, 64);
    }
    if (active && m == 0) {
#pragma unroll
        for (int r = 0; r < 4; ++r) {
            int n = base + q * 4 + r;
            float z = partial[r] + br2[0];
            float sig = 1.f / (1.f + expf(-z));
            float pv = sig * (1.f - (float)term[n]);
            pi[n] = pv;
            float contrib = pv * ccost[n];
            if (contrib != 0.f) atomicAdd(&te[batch[n]], contrib);
        }
    }
}

__global__ void final_kernel(const float* __restrict__ pi,
                             const int* __restrict__ batch,
                             const float* __restrict__ Btot,
                             const float* __restrict__ te,
                             float* __restrict__ out) {
    int n = blockIdx.x * blockDim.x + threadIdx.x;
    if (n >= N_NODES) return;
    int b = batch[n];
    float ratio = fminf(Btot[b] / (te[b] + 1e-12f), 1.f);
    out[n] = pi[n] * ratio;
}

extern "C" void kernel_launch(void* const* d_in, const int* in_sizes, int n_in,
                              void* d_out, int out_size, void* d_ws, size_t ws_size,
                              hipStream_t stream) {
    const float* x     = (const float*)d_in[0];
    const int*   ei    = (const int*)d_in[1];
    const float* ea    = (const float*)d_in[2];
    const int*   batch = (const int*)d_in[3];
    const float* Btot  = (const float*)d_in[4];
    const int*   term  = (const int*)d_in[5];
    const float* ccost = (const float*)d_in[6];
    const float* e1w   = (const float*)d_in[7];
    const float* e1b   = (const float*)d_in[8];
    const float* w1a   = (const float*)d_in[9];
    const float* b1a   = (const float*)d_in[10];
    const float* w1b   = (const float*)d_in[11];
    const float* b1b   = (const float*)d_in[12];
    const float* e2w   = (const float*)d_in[13];
    const float* e2b   = (const float*)d_in[14];
    const float* w2a   = (const float*)d_in[15];
    const float* b2a   = (const float*)d_in[16];
    const float* w2b   = (const float*)d_in[17];
    const float* b2b   = (const float*)d_in[18];
    const float* wr1   = (const float*)d_in[19];
    const float* br1   = (const float*)d_in[20];
    const float* wr2   = (const float*)d_in[21];
    const float* br2   = (const float*)d_in[22];

    char* p = (char*)d_ws;
    int*      bnext  = (int*)p;      p += sizeof(int)      * 1024;      // zeroed (782 used)
    float*    te     = (float*)p;    p += sizeof(float)    * N_GRAPHS;  // zeroed
    int*      starts = (int*)p;      p += sizeof(int)      * N_NODES;
    int*      deg    = (int*)p;      p += sizeof(int)      * N_NODES;
    p = (char*)(((size_t)p + 15) & ~(size_t)15);
    uint2*    ebuk   = (uint2*)p;    p += sizeof(uint2)    * (size_t)N_FBUK * FCAP;
    unsigned* ep4    = (unsigned*)p; p += sizeof(unsigned) * (size_t)N_FBUK * FCAP;
    __half*   h1     = (__half*)p;   p += sizeof(__half)   * (size_t)N_NODES * 64;
    float*    htot   = (float*)p;    p += sizeof(float)    * (size_t)N_NODES * 64;
    float*    xs     = (float*)p;    p += sizeof(float)    * (size_t)N_NODES * 32;
    float*    pi     = (float*)p;    p += sizeof(float)    * N_NODES;
    __half*   pk1Ah  = (__half*)p;   p += sizeof(__half)   * 2048;
    __half*   pk1Al  = (__half*)p;   p += sizeof(__half)   * 2048;
    __half*   pk1Bh  = (__half*)p;   p += sizeof(__half)   * 4096;
    __half*   pk1Bl  = (__half*)p;   p += sizeof(__half)   * 4096;
    __half*   pkAh   = (__half*)p;   p += sizeof(__half)   * 4096;
    __half*   pkAl   = (__half*)p;   p += sizeof(__half)   * 4096;
    __half*   pkBh   = (__half*)p;   p += sizeof(__half)   * 4096;
    __half*   pkBl   = (__half*)p;   p += sizeof(__half)   * 4096;
    __half*   pkRh   = (__half*)p;   p += sizeof(__half)   * 2048;
    __half*   pkRl   = (__half*)p;   p += sizeof(__half)   * 2048;
    float*    out    = (float*)d_out;

    hipMemsetAsync(d_ws, 0, sizeof(int) * 1024 + sizeof(float) * N_GRAPHS, stream);

    bucket_scatter<<<1 + N_SBLK, 512, 0, stream>>>(ei, ea, bnext, ebuk,
                                                   w1a, w1b, w2a, w2b, wr1,
                                                   pk1Ah, pk1Al, pk1Bh, pk1Bl,
                                                   pkAh, pkAl, pkBh, pkBl, pkRh, pkRl);
    bucket_fine<<<N_FBUK, 512, 0, stream>>>(ebuk, bnext, ep4, starts, deg,
                                            x, e1w, e1b, xs);
    node1_kernel<<<(N_NODES / 16 + 3) / 4, 256, 0, stream>>>(xs, pk1Ah, pk1Al, b1a,
                                                             pk1Bh, pk1Bl, b1b, h1);
    aggphase2_kernel<<<(N_NODES + 3) / 4, 256, 0, stream>>>(h1, starts, deg, ep4,
                                                            e2w, e2b, htot);
    node2_kernel<<<(N_NODES / 16 + 3) / 4, 256, 0, stream>>>(htot,
                                                             pkAh, pkAl, b2a,
                                                             pkBh, pkBl, b2b,
                                                             pkRh, pkRl, br1,
                                                             wr2, br2, term,
                                                             batch, ccost, pi, te);
    final_kernel<<<(N_NODES + 255) / 256, 256, 0, stream>>>(pi, batch, Btot, te, out);
}

// Round 11
// 218.861 us; speedup vs baseline: 1.1631x; 1.0244x over previous
//
#include <hip/hip_runtime.h>
#include <hip/hip_fp16.h>
#include <math.h>

#define N_NODES 50000
#define N_EDGES 1600000
#define N_GRAPHS 512
#define F_IN 9
#define H 64
#define EPB 4096
#define N_SBLK ((N_EDGES + EPB - 1) / EPB)   // 391
// 64-node fine buckets: 782 blocks (~3/CU) for sort parallelism
#define BUCKET_NODES 64
#define N_FBUK ((N_NODES + BUCKET_NODES - 1) / BUCKET_NODES)   // 782
#define FCAP 2816                            // mean 2048, sd ~45 -> +17 sd

typedef _Float16 f16x8 __attribute__((ext_vector_type(8)));
typedef float f32x4 __attribute__((ext_vector_type(4)));
typedef float f32x2 __attribute__((ext_vector_type(2)));

__device__ __forceinline__ void pack_weights_body(
        const float* __restrict__ w1a, const float* __restrict__ w1b,
        const float* __restrict__ w2a, const float* __restrict__ w2b,
        const float* __restrict__ wr1,
        __half* __restrict__ pk1Ah, __half* __restrict__ pk1Al,
        __half* __restrict__ pk1Bh, __half* __restrict__ pk1Bl,
        __half* __restrict__ pkAh, __half* __restrict__ pkAl,
        __half* __restrict__ pkBh, __half* __restrict__ pkBl,
        __half* __restrict__ pkRh, __half* __restrict__ pkRl) {
    int t = threadIdx.x;
    for (int i = t; i < 2048; i += 512) {      // w1a: [64][9], K=32 zero-pad
        int j = i & 7, l = (i >> 3) & 63, tt = i >> 9;
        int q = l >> 4, n = l & 15;
        int k = q * 8 + j;
        float v = (k < F_IN) ? w1a[(tt * 16 + n) * F_IN + k] : 0.f;
        __half h = __float2half(v);
        pk1Ah[i] = h; pk1Al[i] = __float2half(v - __half2float(h));
    }
    for (int i = t; i < 4096; i += 512) {
        int j = i & 7, l = (i >> 3) & 63, c = (i >> 9) & 1, tt = i >> 10;
        int q = l >> 4, n = l & 15;
        int src = (tt * 16 + n) * H + c * 32 + q * 8 + j;
        float v1 = w1b[src], wa = w2a[src], wb = w2b[src];
        __half h1 = __float2half(v1), ah = __float2half(wa), bh = __float2half(wb);
        pk1Bh[i] = h1; pk1Bl[i] = __float2half(v1 - __half2float(h1));
        pkAh[i] = ah; pkAl[i] = __float2half(wa - __half2float(ah));
        pkBh[i] = bh; pkBl[i] = __float2half(wb - __half2float(bh));
    }
    for (int i = t; i < 2048; i += 512) {
        int j = i & 7, l = (i >> 3) & 63, c = (i >> 9) & 1, tt = i >> 10;
        int q = l >> 4, n = l & 15;
        float wr = wr1[(tt * 16 + n) * H + c * 32 + q * 8 + j];
        __half rh = __float2half(wr);
        pkRh[i] = rh; pkRl[i] = __float2half(wr - __half2float(rh));
    }
}

// ---------- bucket scatter (fixed-capacity buckets); block 0 packs weights ----------
// rk packing: b(10b)<<19 | dl(6b)<<13 | r(13b)
__global__ void __launch_bounds__(512)
bucket_scatter(const int* __restrict__ ei,
               const float* __restrict__ ea,
               int* __restrict__ bnext,
               uint2* __restrict__ ebuk,
               const float* __restrict__ w1a,
               const float* __restrict__ w1b,
               const float* __restrict__ w2a,
               const float* __restrict__ w2b,
               const float* __restrict__ wr1,
               __half* pk1Ah, __half* pk1Al,
               __half* pk1Bh, __half* pk1Bl,
               __half* pkAh, __half* pkAl,
               __half* pkBh, __half* pkBl,
               __half* pkRh, __half* pkRl) {
    if (blockIdx.x == 0) {
        pack_weights_body(w1a, w1b, w2a, w2b, wr1, pk1Ah, pk1Al, pk1Bh, pk1Bl,
                          pkAh, pkAl, pkBh, pkBl, pkRh, pkRl);
        return;
    }
    __shared__ int cnt[N_FBUK];
    __shared__ int gbase[N_FBUK];
    for (int i = threadIdx.x; i < N_FBUK; i += 512) cnt[i] = 0;
    __syncthreads();
    int base = (blockIdx.x - 1) * EPB;
    int rk[8];
    unsigned pay[8];
#pragma unroll
    for (int j = 0; j < 8; ++j) {
        int e = base + j * 512 + threadIdx.x;
        rk[j] = -1;
        if (e < N_EDGES) {
            int d = ei[N_EDGES + e];
            int s = ei[e];
            float a = ea[e];
            pay[j] = ((unsigned)s << 16) |
                     (unsigned)__half_as_ushort(__float2half(a));
            int b = d >> 6;
            int r = atomicAdd(&cnt[b], 1);
            rk[j] = (b << 19) | ((d & 63) << 13) | r;
        }
    }
    __syncthreads();
    for (int i = threadIdx.x; i < N_FBUK; i += 512)
        gbase[i] = cnt[i] ? atomicAdd(&bnext[i], cnt[i]) : 0;
    __syncthreads();
#pragma unroll
    for (int j = 0; j < 8; ++j) {
        if (rk[j] < 0) continue;
        int b = rk[j] >> 19, dl = (rk[j] >> 13) & 63, r = rk[j] & 8191;
        int slot = gbase[b] + r;
        if (slot >= FCAP) continue;
        ebuk[(size_t)b * FCAP + slot] = make_uint2(pay[j], (unsigned)dl);
    }
}

#define UNPACK_ATTR(P) __half2float(__ushort_as_half((unsigned short)((P) & 0xffffu)))

// ---------- per-bucket fine sort -> node CSR + ep4 + FUSED conv1 aggregation ----------
// 64-node buckets, 782 blocks (~3/CU, 24 waves/CU). After the LDS sort, each of
// the 8 waves aggregates conv1 for 8 nodes straight from LDS (no ep4 re-read).
__global__ void __launch_bounds__(512)
bucket_fine(const uint2* __restrict__ ebuk,
            const int* __restrict__ bnext,
            unsigned* __restrict__ ep4,
            int* __restrict__ starts, int* __restrict__ deg,
            const float* __restrict__ x,
            const float* __restrict__ e1w,
            const float* __restrict__ e1b,
            float* __restrict__ xs) {
    __shared__ unsigned sorted[FCAP];
    __shared__ int cntN[BUCKET_NODES], offN[BUCKET_NODES], nxtN[BUCKET_NODES];
    int b = blockIdx.x;
    int base = b * FCAP;
    int count = bnext[b];
    if (count > FCAP) count = FCAP;
    int tid = threadIdx.x;
    if (tid < BUCKET_NODES) cntN[tid] = 0;
    __syncthreads();
    uint2 ev[6];                                // FCAP/512 = 5.5 -> 6
#pragma unroll
    for (int k = 0; k < 6; ++k) {
        int i = tid + k * 512;
        ev[k] = (i < count) ? ebuk[base + i] : make_uint2(0u, 0xFFFFFFFFu);
    }
#pragma unroll
    for (int k = 0; k < 6; ++k)
        if (ev[k].y < (unsigned)BUCKET_NODES) atomicAdd(&cntN[ev[k].y], 1);
    __syncthreads();
    if (tid < 64) {                     // wave 0: 64-entry scan in one wave
        int v = cntN[tid];
        int incl = v;
#pragma unroll
        for (int off = 1; off < 64; off <<= 1) {
            int t = __shfl_up(incl, off, 64);
            if (tid >= off) incl += t;
        }
        int excl = incl - v;
        offN[tid] = excl;
        nxtN[tid] = 0;
        int n = (b << 6) + tid;
        if (n < N_NODES) { starts[n] = base + excl; deg[n] = v; }
    }
    __syncthreads();
#pragma unroll
    for (int k = 0; k < 6; ++k) {
        if (ev[k].y < (unsigned)BUCKET_NODES) {
            int r = atomicAdd(&nxtN[ev[k].y], 1);
            sorted[offN[ev[k].y] + r] = ev[k].x;
        }
    }
    __syncthreads();
    // write node-sorted edges for conv2's aggregation pass
    for (int i = tid; i < count; i += 512)
        ep4[base + i] = sorted[i];

    // ---- fused conv1 aggregation from LDS (wave w -> nodes w*8 .. w*8+7) ----
    int lane = tid & 63, wid = tid >> 6;
    int slot = lane >> 4;                 // 0..3 edge-ILP slot
    int f = lane & 15;
    bool act = f < F_IN;
    float wf = act ? e1w[f] : 0.f;
    float bf = act ? e1b[f] : 0.f;
#pragma unroll
    for (int i = 0; i < 8; ++i) {
        int nloc = wid * 8 + i;           // wave-uniform
        int n = (b << 6) + nloc;
        if (n >= N_NODES) break;
        int off = offN[nloc];
        int dgN = cntN[nloc];
        float acc = 0.f;
        int j = slot;
        for (; j + 12 < dgN; j += 16) {
            unsigned pa = sorted[off + j];
            unsigned pb = sorted[off + j + 4];
            unsigned pc = sorted[off + j + 8];
            unsigned pd = sorted[off + j + 12];
            float xa_ = act ? x[(pa >> 16) * F_IN + f] : 0.f;
            float xb_ = act ? x[(pb >> 16) * F_IN + f] : 0.f;
            float xc_ = act ? x[(pc >> 16) * F_IN + f] : 0.f;
            float xd_ = act ? x[(pd >> 16) * F_IN + f] : 0.f;
            if (act) {
                acc += fmaxf(xa_ + UNPACK_ATTR(pa) * wf + bf, 0.f)
                     + fmaxf(xb_ + UNPACK_ATTR(pb) * wf + bf, 0.f)
                     + fmaxf(xc_ + UNPACK_ATTR(pc) * wf + bf, 0.f)
                     + fmaxf(xd_ + UNPACK_ATTR(pd) * wf + bf, 0.f);
            }
        }
        for (; j < dgN; j += 4) {
            unsigned p = sorted[off + j];
            float xv = act ? x[(p >> 16) * F_IN + f] : 0.f;
            float m = xv + UNPACK_ATTR(p) * wf + bf;
            acc += act ? fmaxf(m, 0.f) : 0.f;
        }
        acc += __shfl_xor(acc, 16, 64);
        acc += __shfl_xor(acc, 32, 64);
        if (lane < 32) {
            float o = (lane < F_IN) ? x[n * F_IN + lane] + acc : 0.f;
            __builtin_nontemporal_store(o, xs + n * 32 + lane);
        }
    }
}

__device__ __forceinline__ void split8(const float* __restrict__ v,
                                       f16x8& hi, f16x8& lo) {
#pragma unroll
    for (int j = 0; j < 8; ++j) {
        _Float16 h = (_Float16)v[j];
        hi[j] = h;
        lo[j] = (_Float16)(v[j] - (float)h);
    }
}

#define TILE3(C, A0H, A0L, A1H, A1L, PH, PL, T) do {                          \
        f16x8 b0h = *(const f16x8*)((PH) + (((T) * 2 + 0) * 64 + lane) * 8);  \
        f16x8 b0l = *(const f16x8*)((PL) + (((T) * 2 + 0) * 64 + lane) * 8);  \
        f16x8 b1h = *(const f16x8*)((PH) + (((T) * 2 + 1) * 64 + lane) * 8);  \
        f16x8 b1l = *(const f16x8*)((PL) + (((T) * 2 + 1) * 64 + lane) * 8);  \
        C = __builtin_amdgcn_mfma_f32_16x16x32_f16(A0H, b0h, C, 0, 0, 0);     \
        C = __builtin_amdgcn_mfma_f32_16x16x32_f16(A0L, b0h, C, 0, 0, 0);     \
        C = __builtin_amdgcn_mfma_f32_16x16x32_f16(A0H, b0l, C, 0, 0, 0);     \
        C = __builtin_amdgcn_mfma_f32_16x16x32_f16(A1H, b1h, C, 0, 0, 0);     \
        C = __builtin_amdgcn_mfma_f32_16x16x32_f16(A1L, b1h, C, 0, 0, 0);     \
        C = __builtin_amdgcn_mfma_f32_16x16x32_f16(A1H, b1l, C, 0, 0, 0);     \
    } while (0)

// ---------- conv1 node MLP via split-fp16 MFMA; writes interleaved h1[n][64] ----------
__global__ void node1_kernel(const float* __restrict__ xs,
                             const __half* __restrict__ pk1Ah, const __half* __restrict__ pk1Al,
                             const float* __restrict__ b1a,
                             const __half* __restrict__ pk1Bh, const __half* __restrict__ pk1Bl,
                             const float* __restrict__ b1b,
                             __half* __restrict__ h1) {
    __shared__ float hbuf[4][16][68];
    int wv = threadIdx.x >> 6;
    int lane = threadIdx.x & 63;
    int gwave = blockIdx.x * 4 + wv;
    bool active = gwave < (N_NODES / 16);
    int base = active ? gwave * 16 : 0;
    int m = lane & 15, q = lane >> 4;
    const _Float16* pAh = (const _Float16*)pk1Ah;
    const _Float16* pAl = (const _Float16*)pk1Al;
    const _Float16* pBh = (const _Float16*)pk1Bh;
    const _Float16* pBl = (const _Float16*)pk1Bl;

    f16x8 ah, al;
    split8(xs + (size_t)(base + m) * 32 + q * 8, ah, al);
#pragma unroll
    for (int t = 0; t < 4; ++t) {
        f32x4 c = {0.f, 0.f, 0.f, 0.f};
        f16x8 bh = *(const f16x8*)(pAh + (t * 64 + lane) * 8);
        f16x8 bl = *(const f16x8*)(pAl + (t * 64 + lane) * 8);
        c = __builtin_amdgcn_mfma_f32_16x16x32_f16(ah, bh, c, 0, 0, 0);
        c = __builtin_amdgcn_mfma_f32_16x16x32_f16(al, bh, c, 0, 0, 0);
        c = __builtin_amdgcn_mfma_f32_16x16x32_f16(ah, bl, c, 0, 0, 0);
        float bias = b1a[t * 16 + m];
#pragma unroll
        for (int r = 0; r < 4; ++r)
            hbuf[wv][q * 4 + r][t * 16 + m] = fmaxf(c[r] + bias, 0.f);
    }
    __syncthreads();
    f16x8 a0h, a0l, a1h, a1l;
    split8(&hbuf[wv][m][q * 8], a0h, a0l);
    split8(&hbuf[wv][m][32 + q * 8], a1h, a1l);
    float tmp[4][4];
#pragma unroll
    for (int t = 0; t < 4; ++t) {
        f32x4 c = {0.f, 0.f, 0.f, 0.f};
        TILE3(c, a0h, a0l, a1h, a1l, pBh, pBl, t);
        float bias = b1b[t * 16 + m];
#pragma unroll
        for (int r = 0; r < 4; ++r)
            tmp[t][r] = fmaxf(c[r] + bias, 0.f);
    }
    __syncthreads();
#pragma unroll
    for (int t = 0; t < 4; ++t)
#pragma unroll
        for (int r = 0; r < 4; ++r)
            hbuf[wv][q * 4 + r][t * 16 + m] = tmp[t][r];
    __syncthreads();
    if (active) {
        int nn = lane >> 2, part = lane & 3;
        f16x8 vlo, vhi;
        const float* rlo = &hbuf[wv][nn][part * 8];
        const float* rhi = &hbuf[wv][nn][32 + part * 8];
#pragma unroll
        for (int j = 0; j < 8; ++j) {
            vlo[j] = (_Float16)rlo[j];
            vhi[j] = (_Float16)rhi[j];
        }
        *(f16x8*)(h1 + (size_t)(base + nn) * 64 + part * 8) = vlo;
        *(f16x8*)(h1 + (size_t)(base + nn) * 64 + 32 + part * 8) = vhi;
    }
}

// ---------- conv2 aggregation, quad-packed form ----------
// Lane l of quarter-wave q handles features {4l..4l+3} of edge (j+q):
// 4 edges per wave-instruction for both VMEM and VALU. h1 rows read as
// uint2 (4 fp16/lane, 16 lanes = one 128B row). nt store keeps htot out
// of L2 so the h1 gather set stays resident.
__global__ void aggphase2_kernel(const __half* __restrict__ h1,
                                 const int* __restrict__ starts,
                                 const int* __restrict__ deg,
                                 const unsigned* __restrict__ ep4,
                                 const float* __restrict__ ew,
                                 const float* __restrict__ eb,
                                 float* __restrict__ htot) {
    int n = blockIdx.x * (blockDim.x >> 6) + (threadIdx.x >> 6);
    int lane = threadIdx.x & 63;
    if (n >= N_NODES) return;
    int q = lane >> 4;                   // edge slot 0..3
    int l = lane & 15;                   // feature-quad index
    int s0 = starts[n], dg = deg[n];
    const unsigned* ep = ep4 + s0;
    const uint2* h1v = (const uint2*)h1;   // row stride 16 uint2
    float4 w4 = *(const float4*)(ew + 4 * l);
    float4 b4 = *(const float4*)(eb + 4 * l);
    float a0 = 0.f, a1 = 0.f, a2 = 0.f, a3 = 0.f;
#define EDGE4(P, V) do {                                                   \
        float at = UNPACK_ATTR(P);                                         \
        float2 lo = __half22float2(*(const __half2*)&(V).x);               \
        float2 hi = __half22float2(*(const __half2*)&(V).y);               \
        a0 += fmaxf(lo.x + at * w4.x + b4.x, 0.f);                         \
        a1 += fmaxf(lo.y + at * w4.y + b4.y, 0.f);                         \
        a2 += fmaxf(hi.x + at * w4.z + b4.z, 0.f);                         \
        a3 += fmaxf(hi.y + at * w4.w + b4.w, 0.f);                         \
    } while (0)
    int j = 0;
    for (; j + 16 <= dg; j += 16) {
        unsigned p0 = ep[j + q], p1 = ep[j + 4 + q];
        unsigned p2 = ep[j + 8 + q], p3 = ep[j + 12 + q];
        uint2 v0 = h1v[(size_t)(p0 >> 16) * 16 + l];
        uint2 v1 = h1v[(size_t)(p1 >> 16) * 16 + l];
        uint2 v2 = h1v[(size_t)(p2 >> 16) * 16 + l];
        uint2 v3 = h1v[(size_t)(p3 >> 16) * 16 + l];
        EDGE4(p0, v0); EDGE4(p1, v1); EDGE4(p2, v2); EDGE4(p3, v3);
    }
    for (; j + 4 <= dg; j += 4) {
        unsigned p = ep[j + q];
        uint2 v = h1v[(size_t)(p >> 16) * 16 + l];
        EDGE4(p, v);
    }
    int rem = dg - j;
    if (q < rem) {
        unsigned p = ep[j + q];
        uint2 v = h1v[(size_t)(p >> 16) * 16 + l];
        EDGE4(p, v);
    }
#undef EDGE4
    a0 += __shfl_xor(a0, 16, 64); a0 += __shfl_xor(a0, 32, 64);
    a1 += __shfl_xor(a1, 16, 64); a1 += __shfl_xor(a1, 32, 64);
    a2 += __shfl_xor(a2, 16, 64); a2 += __shfl_xor(a2, 32, 64);
    a3 += __shfl_xor(a3, 16, 64); a3 += __shfl_xor(a3, 32, 64);
    if (q == 0) {
        uint2 sv = h1v[(size_t)n * 16 + l];
        float2 lo = __half22float2(*(const __half2*)&sv.x);
        float2 hi = __half22float2(*(const __half2*)&sv.y);
        f32x4 o;
        o[0] = lo.x + a0; o[1] = lo.y + a1; o[2] = hi.x + a2; o[3] = hi.y + a3;
        __builtin_nontemporal_store(o, (f32x4*)(htot + (size_t)n * 64 + 4 * l));
    }
}

// ---------- node2 via split-fp16 MFMA; writes pi and accumulates te ----------
__global__ void node2_kernel(const float* __restrict__ htot,
                             const __half* __restrict__ pkAh, const __half* __restrict__ pkAl,
                             const float* __restrict__ b2a,
                             const __half* __restrict__ pkBh, const __half* __restrict__ pkBl,
                             const float* __restrict__ b2b,
                             const __half* __restrict__ pkRh, const __half* __restrict__ pkRl,
                             const float* __restrict__ br1,
                             const float* __restrict__ wr2,
                             const float* __restrict__ br2,
                             const int* __restrict__ term,
                             const int* __restrict__ batch,
                             const float* __restrict__ ccost,
                             float* __restrict__ pi,
                             float* __restrict__ te) {
    __shared__ float hbuf[4][16][68];
    int wv = threadIdx.x >> 6;
    int lane = threadIdx.x & 63;
    int gwave = blockIdx.x * 4 + wv;
    bool active = gwave < (N_NODES / 16);
    int base = active ? gwave * 16 : 0;
    int m = lane & 15, q = lane >> 4;
    const _Float16* pAh = (const _Float16*)pkAh;
    const _Float16* pAl = (const _Float16*)pkAl;
    const _Float16* pBh = (const _Float16*)pkBh;
    const _Float16* pBl = (const _Float16*)pkBl;
    const _Float16* pRh = (const _Float16*)pkRh;
    const _Float16* pRl = (const _Float16*)pkRl;

    f16x8 a0h, a0l, a1h, a1l;
    {
        const float* hrow = htot + (size_t)(base + m) * 64;
        split8(hrow + q * 8, a0h, a0l);
        split8(hrow + 32 + q * 8, a1h, a1l);
    }
#pragma unroll
    for (int t = 0; t < 4; ++t) {
        f32x4 c = {0.f, 0.f, 0.f, 0.f};
        TILE3(c, a0h, a0l, a1h, a1l, pAh, pAl, t);
        float bias = b2a[t * 16 + m];
#pragma unroll
        for (int r = 0; r < 4; ++r)
            hbuf[wv][q * 4 + r][t * 16 + m] = fmaxf(c[r] + bias, 0.f);
    }
    __syncthreads();
    split8(&hbuf[wv][m][q * 8], a0h, a0l);
    split8(&hbuf[wv][m][32 + q * 8], a1h, a1l);
    float tmp[4][4];
#pragma unroll
    for (int t = 0; t < 4; ++t) {
        f32x4 c = {0.f, 0.f, 0.f, 0.f};
        TILE3(c, a0h, a0l, a1h, a1l, pBh, pBl, t);
        float bias = b2b[t * 16 + m];
#pragma unroll
        for (int r = 0; r < 4; ++r)
            tmp[t][r] = fmaxf(c[r] + bias, 0.f);
    }
    __syncthreads();
#pragma unroll
    for (int t = 0; t < 4; ++t)
#pragma unroll
        for (int r = 0; r < 4; ++r)
            hbuf[wv][q * 4 + r][t * 16 + m] = tmp[t][r];
    __syncthreads();
    split8(&hbuf[wv][m][q * 8], a0h, a0l);
    split8(&hbuf[wv][m][32 + q * 8], a1h, a1l);
    float partial[4] = {0.f, 0.f, 0.f, 0.f};
#pragma unroll
    for (int t = 0; t < 2; ++t) {
        f32x4 c = {0.f, 0.f, 0.f, 0.f};
        TILE3(c, a0h, a0l, a1h, a1l, pRh, pRl, t);
        float bias = br1[t * 16 + m];
        float wv2 = wr2[t * 16 + m];
#pragma unroll
        for (int r = 0; r < 4; ++r)
            partial[r] += fmaxf(c[r] + bias, 0.f) * wv2;
    }
#pragma unroll
    for (int off = 1; off < 16; off <<= 1) {
        partial[0] += __shfl_xor(partial[0], off, 64);
        partial[1] += __shfl_xor(partial[1], off, 64);
        partial[2] += __shfl_xor(partial[2], off, 64);
        partial[3] += __shfl_xor(partial[3], off, 64);
    }
    if (active && m == 0) {
#pragma unroll
        for (int r = 0; r < 4; ++r) {
            int n = base + q * 4 + r;
            float z = partial[r] + br2[0];
            float sig = 1.f / (1.f + expf(-z));
            float pv = sig * (1.f - (float)term[n]);
            pi[n] = pv;
            float contrib = pv * ccost[n];
            if (contrib != 0.f) atomicAdd(&te[batch[n]], contrib);
        }
    }
}

__global__ void final_kernel(const float* __restrict__ pi,
                             const int* __restrict__ batch,
                             const float* __restrict__ Btot,
                             const float* __restrict__ te,
                             float* __restrict__ out) {
    int n = blockIdx.x * blockDim.x + threadIdx.x;
    if (n >= N_NODES) return;
    int b = batch[n];
    float ratio = fminf(Btot[b] / (te[b] + 1e-12f), 1.f);
    out[n] = pi[n] * ratio;
}

extern "C" void kernel_launch(void* const* d_in, const int* in_sizes, int n_in,
                              void* d_out, int out_size, void* d_ws, size_t ws_size,
                              hipStream_t stream) {
    const float* x     = (const float*)d_in[0];
    const int*   ei    = (const int*)d_in[1];
    const float* ea    = (const float*)d_in[2];
    const int*   batch = (const int*)d_in[3];
    const float* Btot  = (const float*)d_in[4];
    const int*   term  = (const int*)d_in[5];
    const float* ccost = (const float*)d_in[6];
    const float* e1w   = (const float*)d_in[7];
    const float* e1b   = (const float*)d_in[8];
    const float* w1a   = (const float*)d_in[9];
    const float* b1a   = (const float*)d_in[10];
    const float* w1b   = (const float*)d_in[11];
    const float* b1b   = (const float*)d_in[12];
    const float* e2w   = (const float*)d_in[13];
    const float* e2b   = (const float*)d_in[14];
    const float* w2a   = (const float*)d_in[15];
    const float* b2a   = (const float*)d_in[16];
    const float* w2b   = (const float*)d_in[17];
    const float* b2b   = (const float*)d_in[18];
    const float* wr1   = (const float*)d_in[19];
    const float* br1   = (const float*)d_in[20];
    const float* wr2   = (const float*)d_in[21];
    const float* br2   = (const float*)d_in[22];

    char* p = (char*)d_ws;
    int*      bnext  = (int*)p;      p += sizeof(int)      * 1024;      // zeroed (782 used)
    float*    te     = (float*)p;    p += sizeof(float)    * N_GRAPHS;  // zeroed
    int*      starts = (int*)p;      p += sizeof(int)      * N_NODES;
    int*      deg    = (int*)p;      p += sizeof(int)      * N_NODES;
    p = (char*)(((size_t)p + 15) & ~(size_t)15);
    uint2*    ebuk   = (uint2*)p;    p += sizeof(uint2)    * (size_t)N_FBUK * FCAP;
    unsigned* ep4    = (unsigned*)p; p += sizeof(unsigned) * (size_t)N_FBUK * FCAP;
    __half*   h1     = (__half*)p;   p += sizeof(__half)   * (size_t)N_NODES * 64;
    float*    htot   = (float*)p;    p += sizeof(float)    * (size_t)N_NODES * 64;
    float*    xs     = (float*)p;    p += sizeof(float)    * (size_t)N_NODES * 32;
    float*    pi     = (float*)p;    p += sizeof(float)    * N_NODES;
    __half*   pk1Ah  = (__half*)p;   p += sizeof(__half)   * 2048;
    __half*   pk1Al  = (__half*)p;   p += sizeof(__half)   * 2048;
    __half*   pk1Bh  = (__half*)p;   p += sizeof(__half)   * 4096;
    __half*   pk1Bl  = (__half*)p;   p += sizeof(__half)   * 4096;
    __half*   pkAh   = (__half*)p;   p += sizeof(__half)   * 4096;
    __half*   pkAl   = (__half*)p;   p += sizeof(__half)   * 4096;
    __half*   pkBh   = (__half*)p;   p += sizeof(__half)   * 4096;
    __half*   pkBl   = (__half*)p;   p += sizeof(__half)   * 4096;
    __half*   pkRh   = (__half*)p;   p += sizeof(__half)   * 2048;
    __half*   pkRl   = (__half*)p;   p += sizeof(__half)   * 2048;
    float*    out    = (float*)d_out;

    hipMemsetAsync(d_ws, 0, sizeof(int) * 1024 + sizeof(float) * N_GRAPHS, stream);

    bucket_scatter<<<1 + N_SBLK, 512, 0, stream>>>(ei, ea, bnext, ebuk,
                                                   w1a, w1b, w2a, w2b, wr1,
                                                   pk1Ah, pk1Al, pk1Bh, pk1Bl,
                                                   pkAh, pkAl, pkBh, pkBl, pkRh, pkRl);
    bucket_fine<<<N_FBUK, 512, 0, stream>>>(ebuk, bnext, ep4, starts, deg,
                                            x, e1w, e1b, xs);
    node1_kernel<<<(N_NODES / 16 + 3) / 4, 256, 0, stream>>>(xs, pk1Ah, pk1Al, b1a,
                                                             pk1Bh, pk1Bl, b1b, h1);
    aggphase2_kernel<<<(N_NODES + 3) / 4, 256, 0, stream>>>(h1, starts, deg, ep4,
                                                            e2w, e2b, htot);
    node2_kernel<<<(N_NODES / 16 + 3) / 4, 256, 0, stream>>>(htot,
                                                             pkAh, pkAl, b2a,
                                                             pkBh, pkBl, b2b,
                                                             pkRh, pkRl, br1,
                                                             wr2, br2, term,
                                                             batch, ccost, pi, te);
    final_kernel<<<(N_NODES + 255) / 256, 256, 0, stream>>>(pi, batch, Btot, te, out);
}

// Round 12
// 217.337 us; speedup vs baseline: 1.1713x; 1.0070x over previous
//
#include <hip/hip_runtime.h>
#include <hip/hip_fp16.h>
#include <math.h>

#define N_NODES 50000
#define N_EDGES 1600000
#define N_GRAPHS 512
#define F_IN 9
#define H 64
#define EPB 4096
#define N_SBLK ((N_EDGES + EPB - 1) / EPB)   // 391
// 64-node fine buckets: 782 blocks (~3/CU) for sort parallelism
#define BUCKET_NODES 64
#define N_FBUK ((N_NODES + BUCKET_NODES - 1) / BUCKET_NODES)   // 782
#define FCAP 2816                            // mean 2048, sd ~45 -> +17 sd

typedef _Float16 f16x8 __attribute__((ext_vector_type(8)));
typedef float f32x4 __attribute__((ext_vector_type(4)));
typedef float f32x2 __attribute__((ext_vector_type(2)));

__device__ __forceinline__ void pack_weights_body(
        const float* __restrict__ w1a, const float* __restrict__ w1b,
        const float* __restrict__ w2a, const float* __restrict__ w2b,
        const float* __restrict__ wr1,
        __half* __restrict__ pk1Ah, __half* __restrict__ pk1Al,
        __half* __restrict__ pk1Bh, __half* __restrict__ pk1Bl,
        __half* __restrict__ pkAh, __half* __restrict__ pkAl,
        __half* __restrict__ pkBh, __half* __restrict__ pkBl,
        __half* __restrict__ pkRh, __half* __restrict__ pkRl) {
    int t = threadIdx.x;
    for (int i = t; i < 2048; i += 512) {      // w1a: [64][9], K=32 zero-pad
        int j = i & 7, l = (i >> 3) & 63, tt = i >> 9;
        int q = l >> 4, n = l & 15;
        int k = q * 8 + j;
        float v = (k < F_IN) ? w1a[(tt * 16 + n) * F_IN + k] : 0.f;
        __half h = __float2half(v);
        pk1Ah[i] = h; pk1Al[i] = __float2half(v - __half2float(h));
    }
    for (int i = t; i < 4096; i += 512) {
        int j = i & 7, l = (i >> 3) & 63, c = (i >> 9) & 1, tt = i >> 10;
        int q = l >> 4, n = l & 15;
        int src = (tt * 16 + n) * H + c * 32 + q * 8 + j;
        float v1 = w1b[src], wa = w2a[src], wb = w2b[src];
        __half h1 = __float2half(v1), ah = __float2half(wa), bh = __float2half(wb);
        pk1Bh[i] = h1; pk1Bl[i] = __float2half(v1 - __half2float(h1));
        pkAh[i] = ah; pkAl[i] = __float2half(wa - __half2float(ah));
        pkBh[i] = bh; pkBl[i] = __float2half(wb - __half2float(bh));
    }
    for (int i = t; i < 2048; i += 512) {
        int j = i & 7, l = (i >> 3) & 63, c = (i >> 9) & 1, tt = i >> 10;
        int q = l >> 4, n = l & 15;
        float wr = wr1[(tt * 16 + n) * H + c * 32 + q * 8 + j];
        __half rh = __float2half(wr);
        pkRh[i] = rh; pkRl[i] = __float2half(wr - __half2float(rh));
    }
}

// ---------- bucket scatter (fixed-capacity buckets); block 0 packs weights ----------
// rk packing: b(10b)<<19 | dl(6b)<<13 | r(13b)
__global__ void __launch_bounds__(512)
bucket_scatter(const int* __restrict__ ei,
               const float* __restrict__ ea,
               int* __restrict__ bnext,
               uint2* __restrict__ ebuk,
               const float* __restrict__ w1a,
               const float* __restrict__ w1b,
               const float* __restrict__ w2a,
               const float* __restrict__ w2b,
               const float* __restrict__ wr1,
               __half* pk1Ah, __half* pk1Al,
               __half* pk1Bh, __half* pk1Bl,
               __half* pkAh, __half* pkAl,
               __half* pkBh, __half* pkBl,
               __half* pkRh, __half* pkRl) {
    if (blockIdx.x == 0) {
        pack_weights_body(w1a, w1b, w2a, w2b, wr1, pk1Ah, pk1Al, pk1Bh, pk1Bl,
                          pkAh, pkAl, pkBh, pkBl, pkRh, pkRl);
        return;
    }
    __shared__ int cnt[N_FBUK];
    __shared__ int gbase[N_FBUK];
    for (int i = threadIdx.x; i < N_FBUK; i += 512) cnt[i] = 0;
    __syncthreads();
    int base = (blockIdx.x - 1) * EPB;
    int rk[8];
    unsigned pay[8];
#pragma unroll
    for (int j = 0; j < 8; ++j) {
        int e = base + j * 512 + threadIdx.x;
        rk[j] = -1;
        if (e < N_EDGES) {
            int d = ei[N_EDGES + e];
            int s = ei[e];
            float a = ea[e];
            pay[j] = ((unsigned)s << 16) |
                     (unsigned)__half_as_ushort(__float2half(a));
            int b = d >> 6;
            int r = atomicAdd(&cnt[b], 1);
            rk[j] = (b << 19) | ((d & 63) << 13) | r;
        }
    }
    __syncthreads();
    for (int i = threadIdx.x; i < N_FBUK; i += 512)
        gbase[i] = cnt[i] ? atomicAdd(&bnext[i], cnt[i]) : 0;
    __syncthreads();
#pragma unroll
    for (int j = 0; j < 8; ++j) {
        if (rk[j] < 0) continue;
        int b = rk[j] >> 19, dl = (rk[j] >> 13) & 63, r = rk[j] & 8191;
        int slot = gbase[b] + r;
        if (slot >= FCAP) continue;
        ebuk[(size_t)b * FCAP + slot] = make_uint2(pay[j], (unsigned)dl);
    }
}

#define UNPACK_ATTR(P) __half2float(__ushort_as_half((unsigned short)((P) & 0xffffu)))

__device__ __forceinline__ void split8(const float* __restrict__ v,
                                       f16x8& hi, f16x8& lo) {
#pragma unroll
    for (int j = 0; j < 8; ++j) {
        _Float16 h = (_Float16)v[j];
        hi[j] = h;
        lo[j] = (_Float16)(v[j] - (float)h);
    }
}

#define TILE3(C, A0H, A0L, A1H, A1L, PH, PL, T) do {                          \
        f16x8 b0h = *(const f16x8*)((PH) + (((T) * 2 + 0) * 64 + lane) * 8);  \
        f16x8 b0l = *(const f16x8*)((PL) + (((T) * 2 + 0) * 64 + lane) * 8);  \
        f16x8 b1h = *(const f16x8*)((PH) + (((T) * 2 + 1) * 64 + lane) * 8);  \
        f16x8 b1l = *(const f16x8*)((PL) + (((T) * 2 + 1) * 64 + lane) * 8);  \
        C = __builtin_amdgcn_mfma_f32_16x16x32_f16(A0H, b0h, C, 0, 0, 0);     \
        C = __builtin_amdgcn_mfma_f32_16x16x32_f16(A0L, b0h, C, 0, 0, 0);     \
        C = __builtin_amdgcn_mfma_f32_16x16x32_f16(A0H, b0l, C, 0, 0, 0);     \
        C = __builtin_amdgcn_mfma_f32_16x16x32_f16(A1H, b1h, C, 0, 0, 0);     \
        C = __builtin_amdgcn_mfma_f32_16x16x32_f16(A1L, b1h, C, 0, 0, 0);     \
        C = __builtin_amdgcn_mfma_f32_16x16x32_f16(A1H, b1l, C, 0, 0, 0);     \
    } while (0)

// ---------- per-bucket fine sort -> CSR + ep4 + FUSED conv1 agg + FUSED node1 MLP ----------
// 64-node buckets, 782 blocks. Phase 1: LDS sort (all 8 waves). Phase 2: conv1
// aggregation from LDS into xs_lds (all 8 waves, 8 nodes each). Phase 3: waves
// 0-3 run the 2-layer MFMA MLP for the block's 4 16-node groups, write h1.
__global__ void __launch_bounds__(512)
bucket_fine(const uint2* __restrict__ ebuk,
            const int* __restrict__ bnext,
            unsigned* __restrict__ ep4,
            int* __restrict__ starts, int* __restrict__ deg,
            const float* __restrict__ x,
            const float* __restrict__ e1w,
            const float* __restrict__ e1b,
            const __half* __restrict__ pk1Ah, const __half* __restrict__ pk1Al,
            const float* __restrict__ b1a,
            const __half* __restrict__ pk1Bh, const __half* __restrict__ pk1Bl,
            const float* __restrict__ b1b,
            __half* __restrict__ h1) {
    __shared__ unsigned sorted[FCAP];
    __shared__ int cntN[BUCKET_NODES], offN[BUCKET_NODES], nxtN[BUCKET_NODES];
    __shared__ float xs_lds[BUCKET_NODES][32];
    __shared__ float hbuf[4][16][68];
    int b = blockIdx.x;
    int base = b * FCAP;
    int count = bnext[b];
    if (count > FCAP) count = FCAP;
    int tid = threadIdx.x;
    if (tid < BUCKET_NODES) cntN[tid] = 0;
    __syncthreads();
    uint2 ev[6];                                // FCAP/512 = 5.5 -> 6
#pragma unroll
    for (int k = 0; k < 6; ++k) {
        int i = tid + k * 512;
        ev[k] = (i < count) ? ebuk[base + i] : make_uint2(0u, 0xFFFFFFFFu);
    }
#pragma unroll
    for (int k = 0; k < 6; ++k)
        if (ev[k].y < (unsigned)BUCKET_NODES) atomicAdd(&cntN[ev[k].y], 1);
    __syncthreads();
    if (tid < 64) {                     // wave 0: 64-entry scan in one wave
        int v = cntN[tid];
        int incl = v;
#pragma unroll
        for (int off = 1; off < 64; off <<= 1) {
            int t = __shfl_up(incl, off, 64);
            if (tid >= off) incl += t;
        }
        int excl = incl - v;
        offN[tid] = excl;
        nxtN[tid] = 0;
        int n = (b << 6) + tid;
        if (n < N_NODES) { starts[n] = base + excl; deg[n] = v; }
    }
    __syncthreads();
#pragma unroll
    for (int k = 0; k < 6; ++k) {
        if (ev[k].y < (unsigned)BUCKET_NODES) {
            int r = atomicAdd(&nxtN[ev[k].y], 1);
            sorted[offN[ev[k].y] + r] = ev[k].x;
        }
    }
    __syncthreads();
    // write node-sorted edges for conv2's aggregation pass
    for (int i = tid; i < count; i += 512)
        ep4[base + i] = sorted[i];

    // ---- fused conv1 aggregation from LDS (wave w -> nodes w*8 .. w*8+7) ----
    int lane = tid & 63, wid = tid >> 6;
    int slot = lane >> 4;                 // 0..3 edge-ILP slot
    int f = lane & 15;
    bool act = f < F_IN;
    float wf = act ? e1w[f] : 0.f;
    float bf = act ? e1b[f] : 0.f;
#pragma unroll
    for (int i = 0; i < 8; ++i) {
        int nloc = wid * 8 + i;           // wave-uniform
        int n = (b << 6) + nloc;
        bool valid = (n < N_NODES);
        int off = offN[nloc];
        int dgN = valid ? cntN[nloc] : 0;
        float acc = 0.f;
        int j = slot;
        for (; j + 12 < dgN; j += 16) {
            unsigned pa = sorted[off + j];
            unsigned pb = sorted[off + j + 4];
            unsigned pc = sorted[off + j + 8];
            unsigned pd = sorted[off + j + 12];
            float xa_ = act ? x[(pa >> 16) * F_IN + f] : 0.f;
            float xb_ = act ? x[(pb >> 16) * F_IN + f] : 0.f;
            float xc_ = act ? x[(pc >> 16) * F_IN + f] : 0.f;
            float xd_ = act ? x[(pd >> 16) * F_IN + f] : 0.f;
            if (act) {
                acc += fmaxf(xa_ + UNPACK_ATTR(pa) * wf + bf, 0.f)
                     + fmaxf(xb_ + UNPACK_ATTR(pb) * wf + bf, 0.f)
                     + fmaxf(xc_ + UNPACK_ATTR(pc) * wf + bf, 0.f)
                     + fmaxf(xd_ + UNPACK_ATTR(pd) * wf + bf, 0.f);
            }
        }
        for (; j < dgN; j += 4) {
            unsigned p = sorted[off + j];
            float xv = act ? x[(p >> 16) * F_IN + f] : 0.f;
            float m = xv + UNPACK_ATTR(p) * wf + bf;
            acc += act ? fmaxf(m, 0.f) : 0.f;
        }
        acc += __shfl_xor(acc, 16, 64);
        acc += __shfl_xor(acc, 32, 64);
        if (lane < 32) {
            float o = 0.f;
            if (valid && lane < F_IN) o = x[n * F_IN + lane] + acc;
            xs_lds[nloc][lane] = o;
        }
    }
    __syncthreads();

    // ---- fused node1 MLP: waves 0-3, wave w -> 16-node group w ----
    bool mlpw = (wid < 4);
    int m = lane & 15, q = lane >> 4;
    const _Float16* pAh = (const _Float16*)pk1Ah;
    const _Float16* pAl = (const _Float16*)pk1Al;
    const _Float16* pBh = (const _Float16*)pk1Bh;
    const _Float16* pBl = (const _Float16*)pk1Bl;
    if (mlpw) {
        f16x8 ah, al;
        split8(&xs_lds[wid * 16 + m][q * 8], ah, al);
#pragma unroll
        for (int t = 0; t < 4; ++t) {
            f32x4 c = {0.f, 0.f, 0.f, 0.f};
            f16x8 bh = *(const f16x8*)(pAh + (t * 64 + lane) * 8);
            f16x8 bl = *(const f16x8*)(pAl + (t * 64 + lane) * 8);
            c = __builtin_amdgcn_mfma_f32_16x16x32_f16(ah, bh, c, 0, 0, 0);
            c = __builtin_amdgcn_mfma_f32_16x16x32_f16(al, bh, c, 0, 0, 0);
            c = __builtin_amdgcn_mfma_f32_16x16x32_f16(ah, bl, c, 0, 0, 0);
            float bias = b1a[t * 16 + m];
#pragma unroll
            for (int r = 0; r < 4; ++r)
                hbuf[wid][q * 4 + r][t * 16 + m] = fmaxf(c[r] + bias, 0.f);
        }
    }
    __syncthreads();
    if (mlpw) {
        f16x8 a0h, a0l, a1h, a1l;
        split8(&hbuf[wid][m][q * 8], a0h, a0l);
        split8(&hbuf[wid][m][32 + q * 8], a1h, a1l);
        float tmp[4][4];
#pragma unroll
        for (int t = 0; t < 4; ++t) {
            f32x4 c = {0.f, 0.f, 0.f, 0.f};
            TILE3(c, a0h, a0l, a1h, a1l, pBh, pBl, t);
            float bias = b1b[t * 16 + m];
#pragma unroll
            for (int r = 0; r < 4; ++r)
                tmp[t][r] = fmaxf(c[r] + bias, 0.f);
        }
        __builtin_amdgcn_s_barrier();   // waves 0-3 internal ordering not needed; hbuf per-wave
#pragma unroll
        for (int t = 0; t < 4; ++t)
#pragma unroll
            for (int r = 0; r < 4; ++r)
                hbuf[wid][q * 4 + r][t * 16 + m] = tmp[t][r];
        // write h1 for this 16-node group
        int nn = lane >> 2, part = lane & 3;
        int n = (b << 6) + wid * 16 + nn;
        if (n < N_NODES) {
            f16x8 vlo, vhi;
            const float* rlo = &hbuf[wid][nn][part * 8];
            const float* rhi = &hbuf[wid][nn][32 + part * 8];
#pragma unroll
            for (int j = 0; j < 8; ++j) {
                vlo[j] = (_Float16)rlo[j];
                vhi[j] = (_Float16)rhi[j];
            }
            *(f16x8*)(h1 + (size_t)n * 64 + part * 8) = vlo;
            *(f16x8*)(h1 + (size_t)n * 64 + 32 + part * 8) = vhi;
        }
    }
}

// ---------- conv2 aggregation, quad-packed form ----------
// Lane l of quarter-wave q handles features {4l..4l+3} of edge (j+q):
// 4 edges per wave-instruction for both VMEM and VALU. h1 rows read as
// uint2 (4 fp16/lane, 16 lanes = one 128B row). nt store keeps htot out
// of L2 so the h1 gather set stays resident.
__global__ void aggphase2_kernel(const __half* __restrict__ h1,
                                 const int* __restrict__ starts,
                                 const int* __restrict__ deg,
                                 const unsigned* __restrict__ ep4,
                                 const float* __restrict__ ew,
                                 const float* __restrict__ eb,
                                 float* __restrict__ htot) {
    int n = blockIdx.x * (blockDim.x >> 6) + (threadIdx.x >> 6);
    int lane = threadIdx.x & 63;
    if (n >= N_NODES) return;
    int q = lane >> 4;                   // edge slot 0..3
    int l = lane & 15;                   // feature-quad index
    int s0 = starts[n], dg = deg[n];
    const unsigned* ep = ep4 + s0;
    const uint2* h1v = (const uint2*)h1;   // row stride 16 uint2
    float4 w4 = *(const float4*)(ew + 4 * l);
    float4 b4 = *(const float4*)(eb + 4 * l);
    float a0 = 0.f, a1 = 0.f, a2 = 0.f, a3 = 0.f;
#define EDGE4(P, V) do {                                                   \
        float at = UNPACK_ATTR(P);                                         \
        float2 lo = __half22float2(*(const __half2*)&(V).x);               \
        float2 hi = __half22float2(*(const __half2*)&(V).y);               \
        a0 += fmaxf(lo.x + at * w4.x + b4.x, 0.f);                         \
        a1 += fmaxf(lo.y + at * w4.y + b4.y, 0.f);                         \
        a2 += fmaxf(hi.x + at * w4.z + b4.z, 0.f);                         \
        a3 += fmaxf(hi.y + at * w4.w + b4.w, 0.f);                         \
    } while (0)
    int j = 0;
    for (; j + 16 <= dg; j += 16) {
        unsigned p0 = ep[j + q], p1 = ep[j + 4 + q];
        unsigned p2 = ep[j + 8 + q], p3 = ep[j + 12 + q];
        uint2 v0 = h1v[(size_t)(p0 >> 16) * 16 + l];
        uint2 v1 = h1v[(size_t)(p1 >> 16) * 16 + l];
        uint2 v2 = h1v[(size_t)(p2 >> 16) * 16 + l];
        uint2 v3 = h1v[(size_t)(p3 >> 16) * 16 + l];
        EDGE4(p0, v0); EDGE4(p1, v1); EDGE4(p2, v2); EDGE4(p3, v3);
    }
    for (; j + 4 <= dg; j += 4) {
        unsigned p = ep[j + q];
        uint2 v = h1v[(size_t)(p >> 16) * 16 + l];
        EDGE4(p, v);
    }
    int rem = dg - j;
    if (q < rem) {
        unsigned p = ep[j + q];
        uint2 v = h1v[(size_t)(p >> 16) * 16 + l];
        EDGE4(p, v);
    }
#undef EDGE4
    a0 += __shfl_xor(a0, 16, 64); a0 += __shfl_xor(a0, 32, 64);
    a1 += __shfl_xor(a1, 16, 64); a1 += __shfl_xor(a1, 32, 64);
    a2 += __shfl_xor(a2, 16, 64); a2 += __shfl_xor(a2, 32, 64);
    a3 += __shfl_xor(a3, 16, 64); a3 += __shfl_xor(a3, 32, 64);
    if (q == 0) {
        uint2 sv = h1v[(size_t)n * 16 + l];
        float2 lo = __half22float2(*(const __half2*)&sv.x);
        float2 hi = __half22float2(*(const __half2*)&sv.y);
        f32x4 o;
        o[0] = lo.x + a0; o[1] = lo.y + a1; o[2] = hi.x + a2; o[3] = hi.y + a3;
        __builtin_nontemporal_store(o, (f32x4*)(htot + (size_t)n * 64 + 4 * l));
    }
}

// ---------- node2 via split-fp16 MFMA; writes pi and accumulates te ----------
__global__ void node2_kernel(const float* __restrict__ htot,
                             const __half* __restrict__ pkAh, const __half* __restrict__ pkAl,
                             const float* __restrict__ b2a,
                             const __half* __restrict__ pkBh, const __half* __restrict__ pkBl,
                             const float* __restrict__ b2b,
                             const __half* __restrict__ pkRh, const __half* __restrict__ pkRl,
                             const float* __restrict__ br1,
                             const float* __restrict__ wr2,
                             const float* __restrict__ br2,
                             const int* __restrict__ term,
                             const int* __restrict__ batch,
                             const float* __restrict__ ccost,
                             float* __restrict__ pi,
                             float* __restrict__ te) {
    __shared__ float hbuf[4][16][68];
    int wv = threadIdx.x >> 6;
    int lane = threadIdx.x & 63;
    int gwave = blockIdx.x * 4 + wv;
    bool active = gwave < (N_NODES / 16);
    int base = active ? gwave * 16 : 0;
    int m = lane & 15, q = lane >> 4;
    const _Float16* pAh = (const _Float16*)pkAh;
    const _Float16* pAl = (const _Float16*)pkAl;
    const _Float16* pBh = (const _Float16*)pkBh;
    const _Float16* pBl = (const _Float16*)pkBl;
    const _Float16* pRh = (const _Float16*)pkRh;
    const _Float16* pRl = (const _Float16*)pkRl;

    f16x8 a0h, a0l, a1h, a1l;
    {
        const float* hrow = htot + (size_t)(base + m) * 64;
        split8(hrow + q * 8, a0h, a0l);
        split8(hrow + 32 + q * 8, a1h, a1l);
    }
#pragma unroll
    for (int t = 0; t < 4; ++t) {
        f32x4 c = {0.f, 0.f, 0.f, 0.f};
        TILE3(c, a0h, a0l, a1h, a1l, pAh, pAl, t);
        float bias = b2a[t * 16 + m];
#pragma unroll
        for (int r = 0; r < 4; ++r)
            hbuf[wv][q * 4 + r][t * 16 + m] = fmaxf(c[r] + bias, 0.f);
    }
    __syncthreads();
    split8(&hbuf[wv][m][q * 8], a0h, a0l);
    split8(&hbuf[wv][m][32 + q * 8], a1h, a1l);
    float tmp[4][4];
#pragma unroll
    for (int t = 0; t < 4; ++t) {
        f32x4 c = {0.f, 0.f, 0.f, 0.f};
        TILE3(c, a0h, a0l, a1h, a1l, pBh, pBl, t);
        float bias = b2b[t * 16 + m];
#pragma unroll
        for (int r = 0; r < 4; ++r)
            tmp[t][r] = fmaxf(c[r] + bias, 0.f);
    }
    __syncthreads();
#pragma unroll
    for (int t = 0; t < 4; ++t)
#pragma unroll
        for (int r = 0; r < 4; ++r)
            hbuf[wv][q * 4 + r][t * 16 + m] = tmp[t][r];
    __syncthreads();
    split8(&hbuf[wv][m][q * 8], a0h, a0l);
    split8(&hbuf[wv][m][32 + q * 8], a1h, a1l);
    float partial[4] = {0.f, 0.f, 0.f, 0.f};
#pragma unroll
    for (int t = 0; t < 2; ++t) {
        f32x4 c = {0.f, 0.f, 0.f, 0.f};
        TILE3(c, a0h, a0l, a1h, a1l, pRh, pRl, t);
        float bias = br1[t * 16 + m];
        float wv2 = wr2[t * 16 + m];
#pragma unroll
        for (int r = 0; r < 4; ++r)
            partial[r] += fmaxf(c[r] + bias, 0.f) * wv2;
    }
#pragma unroll
    for (int off = 1; off < 16; off <<= 1) {
        partial[0] += __shfl_xor(partial[0], off, 64);
        partial[1] += __shfl_xor(partial[1], off, 64);
        partial[2] += __shfl_xor(partial[2], off, 64);
        partial[3] += __shfl_xor(partial[3], off, 64);
    }
    if (active && m == 0) {
#pragma unroll
        for (int r = 0; r < 4; ++r) {
            int n = base + q * 4 + r;
            float z = partial[r] + br2[0];
            float sig = 1.f / (1.f + expf(-z));
            float pv = sig * (1.f - (float)term[n]);
            pi[n] = pv;
            float contrib = pv * ccost[n];
            if (contrib != 0.f) atomicAdd(&te[batch[n]], contrib);
        }
    }
}

__global__ void final_kernel(const float* __restrict__ pi,
                             const int* __restrict__ batch,
                             const float* __restrict__ Btot,
                             const float* __restrict__ te,
                             float* __restrict__ out) {
    int n = blockIdx.x * blockDim.x + threadIdx.x;
    if (n >= N_NODES) return;
    int b = batch[n];
    float ratio = fminf(Btot[b] / (te[b] + 1e-12f), 1.f);
    out[n] = pi[n] * ratio;
}

extern "C" void kernel_launch(void* const* d_in, const int* in_sizes, int n_in,
                              void* d_out, int out_size, void* d_ws, size_t ws_size,
                              hipStream_t stream) {
    const float* x     = (const float*)d_in[0];
    const int*   ei    = (const int*)d_in[1];
    const float* ea    = (const float*)d_in[2];
    const int*   batch = (const int*)d_in[3];
    const float* Btot  = (const float*)d_in[4];
    const int*   term  = (const int*)d_in[5];
    const float* ccost = (const float*)d_in[6];
    const float* e1w   = (const float*)d_in[7];
    const float* e1b   = (const float*)d_in[8];
    const float* w1a   = (const float*)d_in[9];
    const float* b1a   = (const float*)d_in[10];
    const float* w1b   = (const float*)d_in[11];
    const float* b1b   = (const float*)d_in[12];
    const float* e2w   = (const float*)d_in[13];
    const float* e2b   = (const float*)d_in[14];
    const float* w2a   = (const float*)d_in[15];
    const float* b2a   = (const float*)d_in[16];
    const float* w2b   = (const float*)d_in[17];
    const float* b2b   = (const float*)d_in[18];
    const float* wr1   = (const float*)d_in[19];
    const float* br1   = (const float*)d_in[20];
    const float* wr2   = (const float*)d_in[21];
    const float* br2   = (const float*)d_in[22];

    char* p = (char*)d_ws;
    int*      bnext  = (int*)p;      p += sizeof(int)      * 1024;      // zeroed (782 used)
    float*    te     = (float*)p;    p += sizeof(float)    * N_GRAPHS;  // zeroed
    int*      starts = (int*)p;      p += sizeof(int)      * N_NODES;
    int*      deg    = (int*)p;      p += sizeof(int)      * N_NODES;
    p = (char*)(((size_t)p + 15) & ~(size_t)15);
    uint2*    ebuk   = (uint2*)p;    p += sizeof(uint2)    * (size_t)N_FBUK * FCAP;
    unsigned* ep4    = (unsigned*)p; p += sizeof(unsigned) * (size_t)N_FBUK * FCAP;
    __half*   h1     = (__half*)p;   p += sizeof(__half)   * (size_t)N_NODES * 64;
    float*    htot   = (float*)p;    p += sizeof(float)    * (size_t)N_NODES * 64;
    float*    pi     = (float*)p;    p += sizeof(float)    * N_NODES;
    __half*   pk1Ah  = (__half*)p;   p += sizeof(__half)   * 2048;
    __half*   pk1Al  = (__half*)p;   p += sizeof(__half)   * 2048;
    __half*   pk1Bh  = (__half*)p;   p += sizeof(__half)   * 4096;
    __half*   pk1Bl  = (__half*)p;   p += sizeof(__half)   * 4096;
    __half*   pkAh   = (__half*)p;   p += sizeof(__half)   * 4096;
    __half*   pkAl   = (__half*)p;   p += sizeof(__half)   * 4096;
    __half*   pkBh   = (__half*)p;   p += sizeof(__half)   * 4096;
    __half*   pkBl   = (__half*)p;   p += sizeof(__half)   * 4096;
    __half*   pkRh   = (__half*)p;   p += sizeof(__half)   * 2048;
    __half*   pkRl   = (__half*)p;   p += sizeof(__half)   * 2048;
    float*    out    = (float*)d_out;

    hipMemsetAsync(d_ws, 0, sizeof(int) * 1024 + sizeof(float) * N_GRAPHS, stream);

    bucket_scatter<<<1 + N_SBLK, 512, 0, stream>>>(ei, ea, bnext, ebuk,
                                                   w1a, w1b, w2a, w2b, wr1,
                                                   pk1Ah, pk1Al, pk1Bh, pk1Bl,
                                                   pkAh, pkAl, pkBh, pkBl, pkRh, pkRl);
    bucket_fine<<<N_FBUK, 512, 0, stream>>>(ebuk, bnext, ep4, starts, deg,
                                            x, e1w, e1b,
                                            pk1Ah, pk1Al, b1a, pk1Bh, pk1Bl, b1b, h1);
    aggphase2_kernel<<<(N_NODES + 3) / 4, 256, 0, stream>>>(h1, starts, deg, ep4,
                                                            e2w, e2b, htot);
    node2_kernel<<<(N_NODES / 16 + 3) / 4, 256, 0, stream>>>(htot,
                                                             pkAh, pkAl, b2a,
                                                             pkBh, pkBl, b2b,
                                                             pkRh, pkRl, br1,
                                                             wr2, br2, term,
                                                             batch, ccost, pi, te);
    final_kernel<<<(N_NODES + 255) / 256, 256, 0, stream>>>(pi, batch, Btot, te, out);
}